// Round 3
// baseline (1665.117 us; speedup 1.0000x reference)
//
#include <hip/hip_runtime.h>
#include <math.h>

#define B_   2
#define S_   2048
#define H_   1024
#define NH_  16
#define NKV_ 4
#define HD_  64
#define R_   (NH_ / NKV_)   // 4 q-heads per kv-head

// ---------------------------------------------------------------------------
// Generic fp32 GEMM: C[M,N] = A[M,K] @ W[K,N], all row-major contiguous.
// 64x64 block tile, BK=16, 256 threads, 4x4 micro-tile per thread.
// ---------------------------------------------------------------------------
__global__ __launch_bounds__(256) void gemm_f32(const float* __restrict__ A,
                                                const float* __restrict__ W,
                                                float* __restrict__ C,
                                                int M, int N, int K) {
    __shared__ float As[16][68];
    __shared__ float Bs[16][68];

    const int tid  = threadIdx.x;
    const int row0 = blockIdx.y * 64;
    const int col0 = blockIdx.x * 64;
    const int tr   = tid >> 4;
    const int tc   = tid & 15;

    const int ar = tid >> 2;
    const int ac = (tid & 3) << 2;
    const int br = tid >> 4;
    const int bc = (tid & 15) << 2;

    float acc[4][4] = {};

    for (int k0 = 0; k0 < K; k0 += 16) {
        float4 av = *(const float4*)(A + (size_t)(row0 + ar) * K + k0 + ac);
        float4 wv = *(const float4*)(W + (size_t)(k0 + br) * N + col0 + bc);
        As[ac + 0][ar] = av.x;
        As[ac + 1][ar] = av.y;
        As[ac + 2][ar] = av.z;
        As[ac + 3][ar] = av.w;
        *(float4*)&Bs[br][bc] = wv;
        __syncthreads();

#pragma unroll
        for (int kk = 0; kk < 16; kk++) {
            float4 a4 = *(const float4*)&As[kk][tr * 4];
            float4 b4 = *(const float4*)&Bs[kk][tc * 4];
            acc[0][0] += a4.x * b4.x; acc[0][1] += a4.x * b4.y;
            acc[0][2] += a4.x * b4.z; acc[0][3] += a4.x * b4.w;
            acc[1][0] += a4.y * b4.x; acc[1][1] += a4.y * b4.y;
            acc[1][2] += a4.y * b4.z; acc[1][3] += a4.y * b4.w;
            acc[2][0] += a4.z * b4.x; acc[2][1] += a4.z * b4.y;
            acc[2][2] += a4.z * b4.z; acc[2][3] += a4.z * b4.w;
            acc[3][0] += a4.w * b4.x; acc[3][1] += a4.w * b4.y;
            acc[3][2] += a4.w * b4.z; acc[3][3] += a4.w * b4.w;
        }
        __syncthreads();
    }

#pragma unroll
    for (int i = 0; i < 4; i++) {
        float4 ov = { acc[i][0], acc[i][1], acc[i][2], acc[i][3] };
        *(float4*)(C + (size_t)(row0 + tr * 4 + i) * N + col0 + tc * 4) = ov;
    }
}

// ---------------------------------------------------------------------------
// RoPE (in-place on q and k).
// ---------------------------------------------------------------------------
__global__ __launch_bounds__(256) void rope_kernel(float* __restrict__ qb,
                                                   float* __restrict__ kb,
                                                   const float* __restrict__ cosb,
                                                   const float* __restrict__ sinb) {
    const int half = HD_ / 2;  // 32
    int idx = blockIdx.x * blockDim.x + threadIdx.x;
    int token = idx / ((NH_ + NKV_) * half);
    int rem   = idx % ((NH_ + NKV_) * half);
    int head  = rem / half;
    int d     = rem % half;
    int spos  = token % S_;

    float c0 = cosb[spos * HD_ + d];
    float c1 = cosb[spos * HD_ + d + half];
    float s0 = sinb[spos * HD_ + d];
    float s1 = sinb[spos * HD_ + d + half];

    float* p;
    if (head < NH_) p = qb + ((size_t)token * NH_ + head) * HD_;
    else            p = kb + ((size_t)token * NKV_ + (head - NH_)) * HD_;

    float x0 = p[d];
    float x1 = p[d + half];
    p[d]        = x0 * c0 - x1 * s0;
    p[d + half] = x1 * c1 + x0 * s1;
}

// ---------------------------------------------------------------------------
// Flash-style causal GQA attention, v3.
// grid = (S/64, B*NH); block = 256 threads covering 64 query rows.
// Thread (row = tid>>2, hf = (tid>>1)&1, kh = tid&1):
//   - owns query row q0+row's dim-half [hf*32, hf*32+32) in registers
//   - processes only key-half kh (32 of each 64-key tile)
// Per key: 32-dim partial dot, __shfl_xor(2) combines dim halves, exp,
// 32-dim PV-half. At the end the two kh-partial online-softmax states
// (adjacent lanes) are flash-combined via __shfl_xor(1).
// Same total VALU work as v2 but 2x thread parallelism and all 1024
// blocks co-resident (32.25 KB LDS -> 4 blocks/CU).
// ---------------------------------------------------------------------------
__global__ __launch_bounds__(256) void attn_kernel(const float* __restrict__ qb,
                                                   const float* __restrict__ kb,
                                                   const float* __restrict__ vb,
                                                   const float* __restrict__ maskb,
                                                   float* __restrict__ ab) {
    const int tid = threadIdx.x;
    const int bh  = blockIdx.y;
    const int b   = bh / NH_;
    const int h   = bh % NH_;
    const int g   = h / R_;
    const int q0  = blockIdx.x * 64;
    const int kh  = tid & 1;         // key half of each tile
    const int hf  = (tid >> 1) & 1;  // dim half
    const int row = tid >> 2;        // 0..63
    const int q_abs = q0 + row;

    __shared__ float ks[64][HD_];  // 16 KB
    __shared__ float vs[64][HD_];  // 16 KB
    __shared__ float msk[64];

    // q half in registers (8 float4 = 32 floats)
    float4 q[8];
    {
        const float* qp = qb + (((size_t)(b * S_ + q_abs)) * NH_ + h) * HD_ + hf * 32;
#pragma unroll
        for (int i = 0; i < 8; i++) q[i] = ((const float4*)qp)[i];
    }

    float4 o[8] = {};
    float m = -1e30f, l = 0.0f;

    const int koff = kh * 32;
    const int ktiles = blockIdx.x + 1;   // keys up to q0+63 inclusive
    for (int kt = 0; kt < ktiles; kt++) {
        const int base_key = kt * 64;

        // ---- stage K and V tiles (64 keys x 64 dims) + mask ----
#pragma unroll
        for (int i = 0; i < 4; i++) {
            int flat = tid + i * 256;       // 0..1023 float4 slots
            int krow = flat >> 4;           // 0..63
            int col4 = flat & 15;           // 0..15
            size_t goff = (((size_t)(b * S_ + base_key + krow)) * NKV_ + g) * HD_ + col4 * 4;
            *(float4*)&ks[krow][col4 * 4] = *(const float4*)(kb + goff);
            *(float4*)&vs[krow][col4 * 4] = *(const float4*)(vb + goff);
        }
        if (tid < 64) msk[tid] = maskb[b * S_ + base_key + tid];
        __syncthreads();

        // ---- this thread's 32 keys, in 16-key chunks ----
#pragma unroll
        for (int c0 = 0; c0 < 32; c0 += 16) {
            float sc[16];
#pragma unroll
            for (int jj = 0; jj < 16; jj++) {
                const int j = koff + c0 + jj;   // key index within tile
                const float4* kp = (const float4*)&ks[j][hf * 32];
                float4 a = {0.f, 0.f, 0.f, 0.f};
#pragma unroll
                for (int i = 0; i < 8; i++) {
                    float4 kv = kp[i];
                    a.x += q[i].x * kv.x; a.y += q[i].y * kv.y;
                    a.z += q[i].z * kv.z; a.w += q[i].w * kv.w;
                }
                float part = (a.x + a.y) + (a.z + a.w);
                float full = part + __shfl_xor(part, 2);   // combine dim halves
                const int key = base_key + j;
                float val = full * 0.125f + (1.0f - msk[j]) * -1e9f;
                sc[jj] = (key <= q_abs) ? val : -1e30f;
            }
            // chunk max -> merge into running (m, l, o)
            float cmax = sc[0];
#pragma unroll
            for (int jj = 1; jj < 16; jj++) cmax = fmaxf(cmax, sc[jj]);
            float nm    = fmaxf(m, cmax);
            float alpha = __expf(m - nm);
#pragma unroll
            for (int i = 0; i < 8; i++) {
                o[i].x *= alpha; o[i].y *= alpha;
                o[i].z *= alpha; o[i].w *= alpha;
            }
            l *= alpha;
            m = nm;
#pragma unroll
            for (int jj = 0; jj < 16; jj++) {
                float p = __expf(sc[jj] - nm);
                l += p;
                const float4* vp = (const float4*)&vs[koff + c0 + jj][hf * 32];
#pragma unroll
                for (int i = 0; i < 8; i++) {
                    float4 vv = vp[i];
                    o[i].x += p * vv.x; o[i].y += p * vv.y;
                    o[i].z += p * vv.z; o[i].w += p * vv.w;
                }
            }
        }
        __syncthreads();   // reads done before next tile's staging
    }

    // ---- flash-combine the two kh partials (adjacent lanes) ----
    {
        float pm = __shfl_xor(m, 1);
        float nm = fmaxf(m, pm);
        float s  = __expf(m - nm);
        l *= s;
        l += __shfl_xor(l, 1);
#pragma unroll
        for (int i = 0; i < 8; i++) {
            o[i].x *= s; o[i].y *= s; o[i].z *= s; o[i].w *= s;
            o[i].x += __shfl_xor(o[i].x, 1);
            o[i].y += __shfl_xor(o[i].y, 1);
            o[i].z += __shfl_xor(o[i].z, 1);
            o[i].w += __shfl_xor(o[i].w, 1);
        }
    }

    // ---- write normalized output half (kh==0 lane of each pair) ----
    if (kh == 0) {
        float inv = 1.0f / l;
        float* op = ab + (((size_t)(b * S_ + q_abs)) * NH_ + h) * HD_ + hf * 32;
#pragma unroll
        for (int i = 0; i < 8; i++) {
            float4 ov = { o[i].x * inv, o[i].y * inv, o[i].z * inv, o[i].w * inv };
            ((float4*)op)[i] = ov;
        }
    }
}

// ---------------------------------------------------------------------------
extern "C" void kernel_launch(void* const* d_in, const int* in_sizes, int n_in,
                              void* d_out, int out_size, void* d_ws, size_t ws_size,
                              hipStream_t stream) {
    const float* x     = (const float*)d_in[0];
    const float* cosb  = (const float*)d_in[1];
    const float* sinb  = (const float*)d_in[2];
    const float* maskb = (const float*)d_in[3];
    const float* Wq    = (const float*)d_in[4];
    const float* Wk    = (const float*)d_in[5];
    const float* Wv    = (const float*)d_in[6];
    const float* Wo    = (const float*)d_in[7];

    float* qb  = (float*)d_out;                             // consumed before final GEMM
    float* kb  = (float*)d_ws;                              // 1M floats
    float* vb  = kb + (size_t)B_ * S_ * NKV_ * HD_;         // 1M floats
    float* ab  = vb + (size_t)B_ * S_ * NKV_ * HD_;         // 4M floats
    float* out = (float*)d_out;

    const int M = B_ * S_;
    dim3 blk(256);

    gemm_f32<<<dim3((NH_ * HD_) / 64, M / 64), blk, 0, stream>>>(x, Wq, qb, M, NH_ * HD_, H_);
    gemm_f32<<<dim3((NKV_ * HD_) / 64, M / 64), blk, 0, stream>>>(x, Wk, kb, M, NKV_ * HD_, H_);
    gemm_f32<<<dim3((NKV_ * HD_) / 64, M / 64), blk, 0, stream>>>(x, Wv, vb, M, NKV_ * HD_, H_);

    const int nrope = B_ * S_ * (NH_ + NKV_) * (HD_ / 2);
    rope_kernel<<<dim3(nrope / 256), blk, 0, stream>>>(qb, kb, cosb, sinb);

    attn_kernel<<<dim3(S_ / 64, B_ * NH_), blk, 0, stream>>>(qb, kb, vb, maskb, ab);

    gemm_f32<<<dim3(H_ / 64, M / 64), blk, 0, stream>>>(ab, Wo, out, M, H_, H_);
}

// Round 5
// 604.119 us; speedup vs baseline: 2.7563x; 2.7563x over previous
//
#include <hip/hip_runtime.h>
#include <math.h>

#define B_   2
#define S_   2048
#define H_   1024
#define NH_  16
#define NKV_ 4
#define HD_  64
#define R_   (NH_ / NKV_)   // 4 q-heads per kv-head

typedef __attribute__((ext_vector_type(8))) short bf16x8;
typedef __attribute__((ext_vector_type(4))) float f32x4;

__device__ inline short f2bf(float f) {
    unsigned u = __float_as_uint(f);
    u += 0x7FFF + ((u >> 16) & 1);     // RNE to bf16
    return (short)(u >> 16);
}

// ---------------------------------------------------------------------------
// Generic fp32 GEMM: C[M,N] = A[M,K] @ W[K,N]. 64x64 tile, BK=16, 256 thr.
// ---------------------------------------------------------------------------
__global__ __launch_bounds__(256) void gemm_f32(const float* __restrict__ A,
                                                const float* __restrict__ W,
                                                float* __restrict__ C,
                                                int M, int N, int K) {
    __shared__ float As[16][68];
    __shared__ float Bs[16][68];

    const int tid  = threadIdx.x;
    const int row0 = blockIdx.y * 64;
    const int col0 = blockIdx.x * 64;
    const int tr   = tid >> 4;
    const int tc   = tid & 15;

    const int ar = tid >> 2;
    const int ac = (tid & 3) << 2;
    const int br = tid >> 4;
    const int bc = (tid & 15) << 2;

    float acc[4][4] = {};

    for (int k0 = 0; k0 < K; k0 += 16) {
        float4 av = *(const float4*)(A + (size_t)(row0 + ar) * K + k0 + ac);
        float4 wv = *(const float4*)(W + (size_t)(k0 + br) * N + col0 + bc);
        As[ac + 0][ar] = av.x;
        As[ac + 1][ar] = av.y;
        As[ac + 2][ar] = av.z;
        As[ac + 3][ar] = av.w;
        *(float4*)&Bs[br][bc] = wv;
        __syncthreads();

#pragma unroll
        for (int kk = 0; kk < 16; kk++) {
            float4 a4 = *(const float4*)&As[kk][tr * 4];
            float4 b4 = *(const float4*)&Bs[kk][tc * 4];
            acc[0][0] += a4.x * b4.x; acc[0][1] += a4.x * b4.y;
            acc[0][2] += a4.x * b4.z; acc[0][3] += a4.x * b4.w;
            acc[1][0] += a4.y * b4.x; acc[1][1] += a4.y * b4.y;
            acc[1][2] += a4.y * b4.z; acc[1][3] += a4.y * b4.w;
            acc[2][0] += a4.z * b4.x; acc[2][1] += a4.z * b4.y;
            acc[2][2] += a4.z * b4.z; acc[2][3] += a4.z * b4.w;
            acc[3][0] += a4.w * b4.x; acc[3][1] += a4.w * b4.y;
            acc[3][2] += a4.w * b4.z; acc[3][3] += a4.w * b4.w;
        }
        __syncthreads();
    }

#pragma unroll
    for (int i = 0; i < 4; i++) {
        float4 ov = { acc[i][0], acc[i][1], acc[i][2], acc[i][3] };
        *(float4*)(C + (size_t)(row0 + tr * 4 + i) * N + col0 + tc * 4) = ov;
    }
}

// ---------------------------------------------------------------------------
// RoPE (in-place on q and k).
// ---------------------------------------------------------------------------
__global__ __launch_bounds__(256) void rope_kernel(float* __restrict__ qb,
                                                   float* __restrict__ kb,
                                                   const float* __restrict__ cosb,
                                                   const float* __restrict__ sinb) {
    const int half = HD_ / 2;  // 32
    int idx = blockIdx.x * blockDim.x + threadIdx.x;
    int token = idx / ((NH_ + NKV_) * half);
    int rem   = idx % ((NH_ + NKV_) * half);
    int head  = rem / half;
    int d     = rem % half;
    int spos  = token % S_;

    float c0 = cosb[spos * HD_ + d];
    float c1 = cosb[spos * HD_ + d + half];
    float s0 = sinb[spos * HD_ + d];
    float s1 = sinb[spos * HD_ + d + half];

    float* p;
    if (head < NH_) p = qb + ((size_t)token * NH_ + head) * HD_;
    else            p = kb + ((size_t)token * NKV_ + (head - NH_)) * HD_;

    float x0 = p[d];
    float x1 = p[d + half];
    p[d]        = x0 * c0 - x1 * s0;
    p[d + half] = x1 * c1 + x0 * s1;
}

// ---------------------------------------------------------------------------
// bf16 MFMA flash attention (v5.1 — V staging fixed to cover all 64 keys).
// grid = (S/128, B*NH); block = 256 threads (4 waves x 32 q-rows).
// Per wave: 2 row-groups of 16; Q A-frags in regs (loaded once, bf16).
// Per 64-key tile: K staged bf16 LDS [64][72] (pad 8 -> 2-way-free b128),
// V staged TRANSPOSED Vt[d][key] so PV B-frags are contiguous b128.
// QK: 16 mfma -> S (C-layout); online softmax (row = quad*4+i, key = ln);
// P bf16 -> wave-private LDS -> re-read in A-layout; PV: 16 mfma into O.
// Causal-balance swizzle: qt = ((by>>4)&1) ? 15-bx : bx equalizes CU load.
// ---------------------------------------------------------------------------
__global__ __launch_bounds__(256, 2) void attn_kernel(const float* __restrict__ qb,
                                                      const float* __restrict__ kb,
                                                      const float* __restrict__ vb,
                                                      const float* __restrict__ maskb,
                                                      float* __restrict__ ab) {
    const int tid  = threadIdx.x;
    const int w    = tid >> 6;
    const int lane = tid & 63;
    const int ln   = lane & 15;   // "n/m = lane&15" frag coordinate
    const int qd   = lane >> 4;   // quad 0..3

    const int by = blockIdx.y;
    const int b  = by / NH_;
    const int h  = by % NH_;
    const int g  = h / R_;
    const int qt = ((by >> 4) & 1) ? (15 - (int)blockIdx.x) : (int)blockIdx.x;
    const int q0 = qt * 128;
    const int rowb = q0 + w * 32;          // wave's first q-row

    __shared__ short Ks[64 * 72];          // K  [key][dim],  bf16, stride 72
    __shared__ short Vt[64 * 72];          // V^T [dim][key], bf16, stride 72
    __shared__ short Ps[4 * 32 * 72];      // per-wave P [row][key]
    __shared__ float mskS[64];

    // ---- Q A-frags (once): A[m=ln][k=qd*8+j], rows rowb+rg*16+ln ----
    bf16x8 qf[2][2];
#pragma unroll
    for (int rg = 0; rg < 2; rg++) {
        const int row = rowb + rg * 16 + ln;
        const float* qp = qb + (((size_t)(b * S_ + row)) * NH_ + h) * HD_ + qd * 8;
#pragma unroll
        for (int kc = 0; kc < 2; kc++) {
            float4 x0 = *(const float4*)(qp + kc * 32);
            float4 x1 = *(const float4*)(qp + kc * 32 + 4);
            bf16x8 f;
            f[0] = f2bf(x0.x); f[1] = f2bf(x0.y); f[2] = f2bf(x0.z); f[3] = f2bf(x0.w);
            f[4] = f2bf(x1.x); f[5] = f2bf(x1.y); f[6] = f2bf(x1.z); f[7] = f2bf(x1.w);
            qf[rg][kc] = f;
        }
    }

    f32x4 O[2][4] = {};                    // [rg][dt]: row=qd*4+i, dim=dt*16+ln
    float mrow[2][4], lrow[2][4];
#pragma unroll
    for (int rg = 0; rg < 2; rg++)
#pragma unroll
        for (int i = 0; i < 4; i++) { mrow[rg][i] = -1e30f; lrow[rg][i] = 0.0f; }

    const int ktiles = 2 * qt + 2;
    for (int kt = 0; kt < ktiles; kt++) {
        const int base = kt * 64;

        // ---- stage K (coalesced f4 -> bf16 b64 writes) ----
#pragma unroll
        for (int t = 0; t < 4; t++) {
            int flat = tid + t * 256;
            int key  = flat >> 4;
            int c4   = flat & 15;
            float4 kv = *(const float4*)(kb + (((size_t)(b * S_ + base + key)) * NKV_ + g) * HD_ + c4 * 4);
            short4 pk = { f2bf(kv.x), f2bf(kv.y), f2bf(kv.z), f2bf(kv.w) };
            *(short4*)&Ks[key * 72 + c4 * 4] = pk;
        }
        // ---- stage V transposed: 512 (d, key-group) slots, 2 iterations ----
#pragma unroll
        for (int t = 0; t < 2; t++) {
            int flat = tid + t * 256;      // 0..511
            int d    = flat & 63;          // dim
            int kg8  = flat >> 6;          // key-group of 8: 0..7
            const float* vp = vb + (((size_t)(b * S_ + base + kg8 * 8)) * NKV_ + g) * HD_ + d;
            bf16x8 pv;
#pragma unroll
            for (int j = 0; j < 8; j++) pv[j] = f2bf(vp[(size_t)j * NKV_ * HD_]);
            *(bf16x8*)&Vt[d * 72 + kg8 * 8] = pv;
        }
        if (tid < 64) mskS[tid] = maskb[b * S_ + base + tid];
        __syncthreads();

        // ---- QK^T: S[rg][kg] (C-layout: row=qd*4+i, key=kg*16+ln) ----
        f32x4 S[2][4];
#pragma unroll
        for (int kg = 0; kg < 4; kg++) {
            bf16x8 k0 = *(const bf16x8*)&Ks[(kg * 16 + ln) * 72 + qd * 8];
            bf16x8 k1 = *(const bf16x8*)&Ks[(kg * 16 + ln) * 72 + 32 + qd * 8];
#pragma unroll
            for (int rg = 0; rg < 2; rg++) {
                f32x4 z = {0.f, 0.f, 0.f, 0.f};
                z = __builtin_amdgcn_mfma_f32_16x16x32_bf16(qf[rg][0], k0, z, 0, 0, 0);
                S[rg][kg] = __builtin_amdgcn_mfma_f32_16x16x32_bf16(qf[rg][1], k1, z, 0, 0, 0);
            }
        }

        // ---- online softmax + P write ----
        float mt[4];
#pragma unroll
        for (int kg = 0; kg < 4; kg++) mt[kg] = (1.0f - mskS[kg * 16 + ln]) * -1e9f;

#pragma unroll
        for (int rg = 0; rg < 2; rg++) {
            const int rb = rowb + rg * 16 + qd * 4;   // + i
            float sc[4][4];
#pragma unroll
            for (int kg = 0; kg < 4; kg++) {
                const int key = base + kg * 16 + ln;
#pragma unroll
                for (int i = 0; i < 4; i++) {
                    float v = S[rg][kg][i] * 0.125f + mt[kg];
                    sc[kg][i] = (key <= rb + i) ? v : -1e30f;
                }
            }
            float mx[4];
#pragma unroll
            for (int i = 0; i < 4; i++) {
                mx[i] = fmaxf(fmaxf(sc[0][i], sc[1][i]), fmaxf(sc[2][i], sc[3][i]));
                mx[i] = fmaxf(mx[i], __shfl_xor(mx[i], 1));
                mx[i] = fmaxf(mx[i], __shfl_xor(mx[i], 2));
                mx[i] = fmaxf(mx[i], __shfl_xor(mx[i], 4));
                mx[i] = fmaxf(mx[i], __shfl_xor(mx[i], 8));
                float nm    = fmaxf(mrow[rg][i], mx[i]);
                float alpha = __expf(mrow[rg][i] - nm);
                mrow[rg][i] = nm;
                lrow[rg][i] *= alpha;
#pragma unroll
                for (int dt = 0; dt < 4; dt++) O[rg][dt][i] *= alpha;
            }
#pragma unroll
            for (int kg = 0; kg < 4; kg++)
#pragma unroll
                for (int i = 0; i < 4; i++) {
                    float p = __expf(sc[kg][i] - mrow[rg][i]);
                    lrow[rg][i] += p;
                    Ps[w * 2304 + (rg * 16 + qd * 4 + i) * 72 + kg * 16 + ln] = f2bf(p);
                }
        }

        // ---- PV: O += P @ V  (A from Ps, B from Vt) ----
#pragma unroll
        for (int kc2 = 0; kc2 < 2; kc2++) {
            bf16x8 a0 = *(const bf16x8*)&Ps[w * 2304 + (ln)      * 72 + kc2 * 32 + qd * 8];
            bf16x8 a1 = *(const bf16x8*)&Ps[w * 2304 + (16 + ln) * 72 + kc2 * 32 + qd * 8];
#pragma unroll
            for (int dt = 0; dt < 4; dt++) {
                bf16x8 bv = *(const bf16x8*)&Vt[(dt * 16 + ln) * 72 + kc2 * 32 + qd * 8];
                O[0][dt] = __builtin_amdgcn_mfma_f32_16x16x32_bf16(a0, bv, O[0][dt], 0, 0, 0);
                O[1][dt] = __builtin_amdgcn_mfma_f32_16x16x32_bf16(a1, bv, O[1][dt], 0, 0, 0);
            }
        }
        __syncthreads();
    }

    // ---- finalize: reduce l across the 16 key-lanes, normalize, store ----
#pragma unroll
    for (int rg = 0; rg < 2; rg++)
#pragma unroll
        for (int i = 0; i < 4; i++) {
            float l = lrow[rg][i];
            l += __shfl_xor(l, 1);
            l += __shfl_xor(l, 2);
            l += __shfl_xor(l, 4);
            l += __shfl_xor(l, 8);
            float inv = 1.0f / l;
            const int row = rowb + rg * 16 + qd * 4 + i;
            float* op = ab + (((size_t)(b * S_ + row)) * NH_ + h) * HD_ + ln;
#pragma unroll
            for (int dt = 0; dt < 4; dt++) op[dt * 16] = O[rg][dt][i] * inv;
        }
}

// ---------------------------------------------------------------------------
extern "C" void kernel_launch(void* const* d_in, const int* in_sizes, int n_in,
                              void* d_out, int out_size, void* d_ws, size_t ws_size,
                              hipStream_t stream) {
    const float* x     = (const float*)d_in[0];
    const float* cosb  = (const float*)d_in[1];
    const float* sinb  = (const float*)d_in[2];
    const float* maskb = (const float*)d_in[3];
    const float* Wq    = (const float*)d_in[4];
    const float* Wk    = (const float*)d_in[5];
    const float* Wv    = (const float*)d_in[6];
    const float* Wo    = (const float*)d_in[7];

    float* qb  = (float*)d_out;                             // consumed before final GEMM
    float* kb  = (float*)d_ws;                              // 1M floats
    float* vb  = kb + (size_t)B_ * S_ * NKV_ * HD_;         // 1M floats
    float* ab  = vb + (size_t)B_ * S_ * NKV_ * HD_;         // 4M floats
    float* out = (float*)d_out;

    const int M = B_ * S_;
    dim3 blk(256);

    gemm_f32<<<dim3((NH_ * HD_) / 64, M / 64), blk, 0, stream>>>(x, Wq, qb, M, NH_ * HD_, H_);
    gemm_f32<<<dim3((NKV_ * HD_) / 64, M / 64), blk, 0, stream>>>(x, Wk, kb, M, NKV_ * HD_, H_);
    gemm_f32<<<dim3((NKV_ * HD_) / 64, M / 64), blk, 0, stream>>>(x, Wv, vb, M, NKV_ * HD_, H_);

    const int nrope = B_ * S_ * (NH_ + NKV_) * (HD_ / 2);
    rope_kernel<<<dim3(nrope / 256), blk, 0, stream>>>(qb, kb, cosb, sinb);

    attn_kernel<<<dim3(S_ / 128, B_ * NH_), blk, 0, stream>>>(qb, kb, vb, maskb, ab);

    gemm_f32<<<dim3(H_ / 64, M / 64), blk, 0, stream>>>(ab, Wo, out, M, H_, H_);
}

// Round 6
// 281.859 us; speedup vs baseline: 5.9076x; 2.1433x over previous
//
#include <hip/hip_runtime.h>
#include <math.h>

#define B_   2
#define S_   2048
#define H_   1024
#define NH_  16
#define NKV_ 4
#define HD_  64
#define R_   (NH_ / NKV_)   // 4 q-heads per kv-head
#define QKVW 1536           // qkv row width (q 0..1023 | k 1024..1279 | v 1280..1535)

typedef __attribute__((ext_vector_type(8))) short bf16x8;
typedef __attribute__((ext_vector_type(4))) float f32x4;

__device__ inline short f2bf(float f) {
    unsigned u = __float_as_uint(f);
    u += 0x7FFF + ((u >> 16) & 1);     // RNE to bf16
    return (short)(u >> 16);
}
__device__ inline float bf2f(short u) {
    return __uint_as_float(((unsigned)(unsigned short)u) << 16);
}

// async global->LDS, 16 B per lane; lptr is the wave-uniform chunk base,
// HW scatters lane i's 16 B at lptr + i*16 (m97/m104 semantics).
__device__ inline void gload_lds16(const void* gptr, void* lptr) {
    __builtin_amdgcn_global_load_lds(
        (const __attribute__((address_space(1))) unsigned int*)gptr,
        (__attribute__((address_space(3))) unsigned int*)lptr,
        16, 0, 0);
}

// ---------------------------------------------------------------------------
// x (fp32, row-major) -> bf16, elementwise. 8 elems/thread.
// ---------------------------------------------------------------------------
__global__ __launch_bounds__(256) void convert_x(const float* __restrict__ x,
                                                 short* __restrict__ xh) {
    int idx = blockIdx.x * 256 + threadIdx.x;
    const float4* xp = (const float4*)(x + (size_t)idx * 8);
    float4 a = xp[0], b = xp[1];
    bf16x8 o;
    o[0] = f2bf(a.x); o[1] = f2bf(a.y); o[2] = f2bf(a.z); o[3] = f2bf(a.w);
    o[4] = f2bf(b.x); o[5] = f2bf(b.y); o[6] = f2bf(b.z); o[7] = f2bf(b.w);
    *(bf16x8*)(xh + (size_t)idx * 8) = o;
}

// ---------------------------------------------------------------------------
// Wt[n][k] = bf16(W[k][n]); W is K x N fp32. 64x64 LDS-tiled transpose.
// ---------------------------------------------------------------------------
__global__ __launch_bounds__(256) void tconv(const float* __restrict__ W,
                                             short* __restrict__ Wt,
                                             int K, int N) {
    __shared__ short T[64][68];
    const int k0 = blockIdx.y * 64, n0 = blockIdx.x * 64;
    const int tid = threadIdx.x;
    const int r  = tid >> 4;
    const int c4 = (tid & 15) * 4;
#pragma unroll
    for (int t = 0; t < 4; t++) {
        int row = t * 16 + r;
        float4 v = *(const float4*)&W[(size_t)(k0 + row) * N + n0 + c4];
        T[c4 + 0][row] = f2bf(v.x);
        T[c4 + 1][row] = f2bf(v.y);
        T[c4 + 2][row] = f2bf(v.z);
        T[c4 + 3][row] = f2bf(v.w);
    }
    __syncthreads();
#pragma unroll
    for (int t = 0; t < 4; t++) {
        int row = t * 16 + r;          // n index
        short4 o = *(short4*)&T[row][c4];
        *(short4*)&Wt[(size_t)(n0 + row) * K + k0 + c4] = o;
    }
}

// ---------------------------------------------------------------------------
// bf16 MFMA GEMM, B^T form (m97 structure): C[M,N] = A[M,K] @ Bt[N,K]^T.
// 128x128 block tile, BK=32, 256 threads = 4 waves (2x2 of 64x64).
// global_load_lds width=16 staging; 16x16x32 MFMA; fp32 acc.
// OUT_BF16: C stored bf16 (ldc in elements), else fp32.
// ---------------------------------------------------------------------------
template <int OUT_BF16>
__global__ __launch_bounds__(256) void gemm_bt_bf16(const short* __restrict__ A, int lda,
                                                    const short* __restrict__ Bt,
                                                    void* __restrict__ C, int ldc,
                                                    int K) {
    __shared__ short Ah[128 * 32];   // [row][k] 8 KB, unpadded (glds layout)
    __shared__ short Bh[128 * 32];   // [col][k] 8 KB

    const int tid  = threadIdx.x;
    const int w    = tid >> 6;
    const int lane = tid & 63;
    const int ln   = lane & 15;
    const int qd   = lane >> 4;
    const int wr   = w >> 1, wc = w & 1;
    const int row0 = blockIdx.y * 128;
    const int col0 = blockIdx.x * 128;

    const int sr = lane >> 2;        // 0..15
    const int sk = (lane & 3) * 8;   // k element offset

    f32x4 acc[4][4];
#pragma unroll
    for (int mi = 0; mi < 4; mi++)
#pragma unroll
        for (int ni = 0; ni < 4; ni++)
            acc[mi][ni] = (f32x4){0.f, 0.f, 0.f, 0.f};

    for (int k0 = 0; k0 < K; k0 += 32) {
        __syncthreads();   // previous iter's frag reads done
#pragma unroll
        for (int t = 0; t < 2; t++) {
            const int rr = w * 32 + t * 16;      // chunk base row/col
            gload_lds16(A  + (size_t)(row0 + rr + sr) * lda + k0 + sk, &Ah[rr * 32]);
            gload_lds16(Bt + (size_t)(col0 + rr + sr) * K   + k0 + sk, &Bh[rr * 32]);
        }
        __syncthreads();   // vmcnt(0) drain inserted by compiler

        bf16x8 af[4], bf[4];
#pragma unroll
        for (int i = 0; i < 4; i++) {
            af[i] = *(const bf16x8*)&Ah[(wr * 64 + i * 16 + ln) * 32 + qd * 8];
            bf[i] = *(const bf16x8*)&Bh[(wc * 64 + i * 16 + ln) * 32 + qd * 8];
        }
#pragma unroll
        for (int mi = 0; mi < 4; mi++)
#pragma unroll
            for (int ni = 0; ni < 4; ni++)
                acc[mi][ni] = __builtin_amdgcn_mfma_f32_16x16x32_bf16(af[mi], bf[ni], acc[mi][ni], 0, 0, 0);
    }

    // epilogue: C(row0+wr*64+mi*16+qd*4+i, col0+wc*64+ni*16+ln)
#pragma unroll
    for (int mi = 0; mi < 4; mi++)
#pragma unroll
        for (int i = 0; i < 4; i++) {
            const size_t row = row0 + wr * 64 + mi * 16 + qd * 4 + i;
            if (OUT_BF16) {
                short* Cp = (short*)C + row * ldc + col0 + wc * 64 + ln;
#pragma unroll
                for (int ni = 0; ni < 4; ni++) Cp[ni * 16] = f2bf(acc[mi][ni][i]);
            } else {
                float* Cp = (float*)C + row * ldc + col0 + wc * 64 + ln;
#pragma unroll
                for (int ni = 0; ni < 4; ni++) Cp[ni * 16] = acc[mi][ni][i];
            }
        }
}

// ---------------------------------------------------------------------------
// RoPE in-place on bf16 qkv (token stride QKVW). 8 dims/thread.
// head 0..15 = q at col h*64; head 16..19 = k at col 1024+(h-16)*64.
// ---------------------------------------------------------------------------
__global__ __launch_bounds__(256) void rope_bf16(short* __restrict__ qkv,
                                                 const float* __restrict__ cosb,
                                                 const float* __restrict__ sinb) {
    int idx   = blockIdx.x * 256 + threadIdx.x;   // B*S*20*4 total
    int oct   = idx & 3;
    int head  = (idx >> 2) % 20;
    int token = idx / 80;
    int spos  = token % S_;
    int d0    = oct * 8;
    int coff  = (head < NH_) ? head * HD_ : H_ + (head - NH_) * HD_;

    short* p = qkv + (size_t)token * QKVW + coff;
    bf16x8 lo = *(bf16x8*)&p[d0];
    bf16x8 hi = *(bf16x8*)&p[d0 + 32];
    const float* cp = cosb + (size_t)spos * HD_;
    const float* sp = sinb + (size_t)spos * HD_;
    bf16x8 nlo, nhi;
#pragma unroll
    for (int j = 0; j < 8; j++) {
        float x0 = bf2f(lo[j]), x1 = bf2f(hi[j]);
        float c0 = cp[d0 + j], c1 = cp[d0 + 32 + j];
        float s0 = sp[d0 + j], s1 = sp[d0 + 32 + j];
        nlo[j] = f2bf(x0 * c0 - x1 * s0);
        nhi[j] = f2bf(x1 * c1 + x0 * s1);
    }
    *(bf16x8*)&p[d0]      = nlo;
    *(bf16x8*)&p[d0 + 32] = nhi;
}

// ---------------------------------------------------------------------------
// bf16 MFMA flash attention (v6 — bf16-native I/O on the packed qkv buffer).
// grid = (S/128, B*NH); block = 256 (4 waves x 32 q-rows).
// Output (bf16) is written into the consumed q-slice of qkv: each block
// overwrites only its own rows x head-cols, which no other block reads.
// ---------------------------------------------------------------------------
__global__ __launch_bounds__(256, 2) void attn_kernel(short* __restrict__ qkv,
                                                      const float* __restrict__ maskb) {
    const int tid  = threadIdx.x;
    const int w    = tid >> 6;
    const int lane = tid & 63;
    const int ln   = lane & 15;
    const int qd   = lane >> 4;

    const int by = blockIdx.y;
    const int b  = by / NH_;
    const int h  = by % NH_;
    const int g  = h / R_;
    const int qt = ((by >> 4) & 1) ? (15 - (int)blockIdx.x) : (int)blockIdx.x;
    const int q0 = qt * 128;
    const int rowb = q0 + w * 32;

    __shared__ short Ks[64 * 72];          // K  [key][dim], stride 72
    __shared__ short Vt[64 * 72];          // V^T [dim][key]
    __shared__ short Ps[4 * 32 * 72];      // per-wave P [row][key]
    __shared__ float mskS[64];

    // ---- Q A-frags (direct bf16 loads) ----
    bf16x8 qf[2][2];
#pragma unroll
    for (int rg = 0; rg < 2; rg++) {
        const int row = rowb + rg * 16 + ln;
        const short* qp = qkv + (size_t)(b * S_ + row) * QKVW + h * HD_;
        qf[rg][0] = *(const bf16x8*)&qp[qd * 8];
        qf[rg][1] = *(const bf16x8*)&qp[32 + qd * 8];
    }

    f32x4 O[2][4] = {};
    float mrow[2][4], lrow[2][4];
#pragma unroll
    for (int rg = 0; rg < 2; rg++)
#pragma unroll
        for (int i = 0; i < 4; i++) { mrow[rg][i] = -1e30f; lrow[rg][i] = 0.0f; }

    const int ktiles = 2 * qt + 2;
    for (int kt = 0; kt < ktiles; kt++) {
        const int base = kt * 64;

        // ---- stage K (bf16x8 copies, 512 slots over 2 iters) ----
#pragma unroll
        for (int t = 0; t < 2; t++) {
            int flat = tid + t * 256;
            int key  = flat >> 3;
            int c8   = flat & 7;
            const short* kp = qkv + (size_t)(b * S_ + base + key) * QKVW + H_ + g * HD_ + c8 * 8;
            *(bf16x8*)&Ks[key * 72 + c8 * 8] = *(const bf16x8*)kp;
        }
        // ---- stage V transposed ----
#pragma unroll
        for (int t = 0; t < 2; t++) {
            int flat = tid + t * 256;
            int d    = flat & 63;
            int kg8  = flat >> 6;
            const short* vp = qkv + (size_t)(b * S_ + base + kg8 * 8) * QKVW + H_ + NKV_ * HD_ + g * HD_ + d;
            bf16x8 pv;
#pragma unroll
            for (int j = 0; j < 8; j++) pv[j] = vp[(size_t)j * QKVW];
            *(bf16x8*)&Vt[d * 72 + kg8 * 8] = pv;
        }
        if (tid < 64) mskS[tid] = maskb[b * S_ + base + tid];
        __syncthreads();

        // ---- QK^T ----
        f32x4 S[2][4];
#pragma unroll
        for (int kg = 0; kg < 4; kg++) {
            bf16x8 k0 = *(const bf16x8*)&Ks[(kg * 16 + ln) * 72 + qd * 8];
            bf16x8 k1 = *(const bf16x8*)&Ks[(kg * 16 + ln) * 72 + 32 + qd * 8];
#pragma unroll
            for (int rg = 0; rg < 2; rg++) {
                f32x4 z = {0.f, 0.f, 0.f, 0.f};
                z = __builtin_amdgcn_mfma_f32_16x16x32_bf16(qf[rg][0], k0, z, 0, 0, 0);
                S[rg][kg] = __builtin_amdgcn_mfma_f32_16x16x32_bf16(qf[rg][1], k1, z, 0, 0, 0);
            }
        }

        // ---- online softmax + P write ----
        float mt[4];
#pragma unroll
        for (int kg = 0; kg < 4; kg++) mt[kg] = (1.0f - mskS[kg * 16 + ln]) * -1e9f;

#pragma unroll
        for (int rg = 0; rg < 2; rg++) {
            const int rb = rowb + rg * 16 + qd * 4;
            float sc[4][4];
#pragma unroll
            for (int kg = 0; kg < 4; kg++) {
                const int key = base + kg * 16 + ln;
#pragma unroll
                for (int i = 0; i < 4; i++) {
                    float v = S[rg][kg][i] * 0.125f + mt[kg];
                    sc[kg][i] = (key <= rb + i) ? v : -1e30f;
                }
            }
#pragma unroll
            for (int i = 0; i < 4; i++) {
                float mx = fmaxf(fmaxf(sc[0][i], sc[1][i]), fmaxf(sc[2][i], sc[3][i]));
                mx = fmaxf(mx, __shfl_xor(mx, 1));
                mx = fmaxf(mx, __shfl_xor(mx, 2));
                mx = fmaxf(mx, __shfl_xor(mx, 4));
                mx = fmaxf(mx, __shfl_xor(mx, 8));
                float nm    = fmaxf(mrow[rg][i], mx);
                float alpha = __expf(mrow[rg][i] - nm);
                mrow[rg][i] = nm;
                lrow[rg][i] *= alpha;
#pragma unroll
                for (int dt = 0; dt < 4; dt++) O[rg][dt][i] *= alpha;
            }
#pragma unroll
            for (int kg = 0; kg < 4; kg++)
#pragma unroll
                for (int i = 0; i < 4; i++) {
                    float p = __expf(sc[kg][i] - mrow[rg][i]);
                    lrow[rg][i] += p;
                    Ps[w * 2304 + (rg * 16 + qd * 4 + i) * 72 + kg * 16 + ln] = f2bf(p);
                }
        }

        // ---- PV ----
#pragma unroll
        for (int kc2 = 0; kc2 < 2; kc2++) {
            bf16x8 a0 = *(const bf16x8*)&Ps[w * 2304 + (ln)      * 72 + kc2 * 32 + qd * 8];
            bf16x8 a1 = *(const bf16x8*)&Ps[w * 2304 + (16 + ln) * 72 + kc2 * 32 + qd * 8];
#pragma unroll
            for (int dt = 0; dt < 4; dt++) {
                bf16x8 bv = *(const bf16x8*)&Vt[(dt * 16 + ln) * 72 + kc2 * 32 + qd * 8];
                O[0][dt] = __builtin_amdgcn_mfma_f32_16x16x32_bf16(a0, bv, O[0][dt], 0, 0, 0);
                O[1][dt] = __builtin_amdgcn_mfma_f32_16x16x32_bf16(a1, bv, O[1][dt], 0, 0, 0);
            }
        }
        __syncthreads();
    }

    // ---- finalize: write bf16 into the q-slice (own rows/cols only) ----
#pragma unroll
    for (int rg = 0; rg < 2; rg++)
#pragma unroll
        for (int i = 0; i < 4; i++) {
            float l = lrow[rg][i];
            l += __shfl_xor(l, 1);
            l += __shfl_xor(l, 2);
            l += __shfl_xor(l, 4);
            l += __shfl_xor(l, 8);
            float inv = 1.0f / l;
            const int row = rowb + rg * 16 + qd * 4 + i;
            short* op = qkv + (size_t)(b * S_ + row) * QKVW + h * HD_ + ln;
#pragma unroll
            for (int dt = 0; dt < 4; dt++) op[dt * 16] = f2bf(O[rg][dt][i] * inv);
        }
}

// ---------------------------------------------------------------------------
extern "C" void kernel_launch(void* const* d_in, const int* in_sizes, int n_in,
                              void* d_out, int out_size, void* d_ws, size_t ws_size,
                              hipStream_t stream) {
    const float* x     = (const float*)d_in[0];
    const float* cosb  = (const float*)d_in[1];
    const float* sinb  = (const float*)d_in[2];
    const float* maskb = (const float*)d_in[3];
    const float* Wq    = (const float*)d_in[4];
    const float* Wk    = (const float*)d_in[5];
    const float* Wv    = (const float*)d_in[6];
    const float* Wo    = (const float*)d_in[7];

    const int M = B_ * S_;   // 4096

    // xh (bf16 x) lives in d_out[0, 8MB) — consumed by GEMM1 before GEMM2
    // rewrites d_out.  ws: qkv bf16 | Wqkvt bf16 | Wot bf16  (17.8 MB).
    short* xh    = (short*)d_out;
    short* qkv   = (short*)d_ws;                     // [4096][1536]
    short* Wqkvt = qkv + (size_t)M * QKVW;           // [1536][1024]
    short* Wot   = Wqkvt + (size_t)QKVW * H_;        // [1024][1024]
    float* out   = (float*)d_out;

    dim3 blk(256);

    convert_x<<<dim3((M * H_) / (8 * 256)), blk, 0, stream>>>(x, xh);

    tconv<<<dim3(H_ / 64, H_ / 64), blk, 0, stream>>>(Wq, Wqkvt, H_, H_);
    tconv<<<dim3((NKV_ * HD_) / 64, H_ / 64), blk, 0, stream>>>(Wk, Wqkvt + (size_t)H_ * H_, H_, NKV_ * HD_);
    tconv<<<dim3((NKV_ * HD_) / 64, H_ / 64), blk, 0, stream>>>(Wv, Wqkvt + (size_t)(H_ + NKV_ * HD_) * H_, H_, NKV_ * HD_);
    tconv<<<dim3(H_ / 64, H_ / 64), blk, 0, stream>>>(Wo, Wot, H_, H_);

    // GEMM1: qkv = xh @ Wqkvt^T  (bf16 out)
    gemm_bt_bf16<1><<<dim3(QKVW / 128, M / 128), blk, 0, stream>>>(xh, H_, Wqkvt, qkv, QKVW, H_);

    rope_bf16<<<dim3((M * 20 * 4) / 256), blk, 0, stream>>>(qkv, cosb, sinb);

    attn_kernel<<<dim3(S_ / 128, B_ * NH_), blk, 0, stream>>>(qkv, maskb);

    // GEMM2: out = attn_out(q-slice of qkv, lda=1536) @ Wot^T  (fp32 out)
    gemm_bt_bf16<0><<<dim3(H_ / 128, M / 128), blk, 0, stream>>>(qkv, QKVW, Wot, out, H_, H_);
}

// Round 7
// 260.549 us; speedup vs baseline: 6.3908x; 1.0818x over previous
//
#include <hip/hip_runtime.h>
#include <math.h>

#define B_   2
#define S_   2048
#define H_   1024
#define NH_  16
#define NKV_ 4
#define HD_  64
#define R_   (NH_ / NKV_)   // 4 q-heads per kv-head
#define QKVW 1536           // qkv row width (q 0..1023 | k 1024..1279 | v 1280..1535)

typedef __attribute__((ext_vector_type(8))) short bf16x8;
typedef __attribute__((ext_vector_type(4))) float f32x4;

__device__ inline short f2bf(float f) {
    unsigned u = __float_as_uint(f);
    u += 0x7FFF + ((u >> 16) & 1);     // RNE to bf16
    return (short)(u >> 16);
}
__device__ inline float bf2f(short u) {
    return __uint_as_float(((unsigned)(unsigned short)u) << 16);
}

// async global->LDS, 16 B per lane; lptr is the wave-uniform chunk base,
// HW scatters lane i's 16 B at lptr + i*16 (m97/m104 semantics).
__device__ inline void gload_lds16(const void* gptr, void* lptr) {
    __builtin_amdgcn_global_load_lds(
        (const __attribute__((address_space(1))) unsigned int*)gptr,
        (__attribute__((address_space(3))) unsigned int*)lptr,
        16, 0, 0);
}

// ---------------------------------------------------------------------------
// x (fp32, row-major) -> bf16, elementwise. 8 elems/thread.
// ---------------------------------------------------------------------------
__global__ __launch_bounds__(256) void convert_x(const float* __restrict__ x,
                                                 short* __restrict__ xh) {
    int idx = blockIdx.x * 256 + threadIdx.x;
    const float4* xp = (const float4*)(x + (size_t)idx * 8);
    float4 a = xp[0], b = xp[1];
    bf16x8 o;
    o[0] = f2bf(a.x); o[1] = f2bf(a.y); o[2] = f2bf(a.z); o[3] = f2bf(a.w);
    o[4] = f2bf(b.x); o[5] = f2bf(b.y); o[6] = f2bf(b.z); o[7] = f2bf(b.w);
    *(bf16x8*)(xh + (size_t)idx * 8) = o;
}

// ---------------------------------------------------------------------------
// Wt[n][k] = bf16(W[k][n]); W is K x N fp32. 64x64 LDS-tiled transpose.
// ---------------------------------------------------------------------------
__global__ __launch_bounds__(256) void tconv(const float* __restrict__ W,
                                             short* __restrict__ Wt,
                                             int K, int N) {
    __shared__ short T[64][68];
    const int k0 = blockIdx.y * 64, n0 = blockIdx.x * 64;
    const int tid = threadIdx.x;
    const int r  = tid >> 4;
    const int c4 = (tid & 15) * 4;
#pragma unroll
    for (int t = 0; t < 4; t++) {
        int row = t * 16 + r;
        float4 v = *(const float4*)&W[(size_t)(k0 + row) * N + n0 + c4];
        T[c4 + 0][row] = f2bf(v.x);
        T[c4 + 1][row] = f2bf(v.y);
        T[c4 + 2][row] = f2bf(v.z);
        T[c4 + 3][row] = f2bf(v.w);
    }
    __syncthreads();
#pragma unroll
    for (int t = 0; t < 4; t++) {
        int row = t * 16 + r;          // n index
        short4 o = *(short4*)&T[row][c4];
        *(short4*)&Wt[(size_t)(n0 + row) * K + k0 + c4] = o;
    }
}

// ---------------------------------------------------------------------------
// V transpose pre-pass: Vtg[(b*NKV+g)*HD + d][s] = qkv v-slice (bf16).
// One thread per (bg, d, 8-token chunk). Reads coalesced (lanes span d),
// writes 16 B scattered (stride S*2B) — tiny total (2 MB).
// ---------------------------------------------------------------------------
__global__ __launch_bounds__(256) void vtrans(const short* __restrict__ qkv,
                                              short* __restrict__ Vtg) {
    int flat = blockIdx.x * 256 + threadIdx.x;
    int d  = flat & 63;
    int s8 = (flat >> 6) & (S_ / 8 - 1);
    int bg = flat >> 14;               // 0..7
    int b  = bg >> 2;
    int g  = bg & 3;
    const short* vp = qkv + ((size_t)(b * S_ + s8 * 8)) * QKVW + H_ + NKV_ * HD_ + g * HD_ + d;
    bf16x8 o;
#pragma unroll
    for (int j = 0; j < 8; j++) o[j] = vp[(size_t)j * QKVW];
    *(bf16x8*)&Vtg[((size_t)bg * HD_ + d) * S_ + s8 * 8] = o;
}

// ---------------------------------------------------------------------------
// bf16 MFMA GEMM, B^T form (m97 structure): C[M,N] = A[M,K] @ Bt[N,K]^T.
// 128x128 block tile, BK=32, 256 threads = 4 waves (2x2 of 64x64).
// global_load_lds width=16 staging; 16x16x32 MFMA; fp32 acc.
// OUT_BF16: C stored bf16 (ldc in elements), else fp32.
// ---------------------------------------------------------------------------
template <int OUT_BF16>
__global__ __launch_bounds__(256) void gemm_bt_bf16(const short* __restrict__ A, int lda,
                                                    const short* __restrict__ Bt,
                                                    void* __restrict__ C, int ldc,
                                                    int K) {
    __shared__ short Ah[128 * 32];   // [row][k] 8 KB, unpadded (glds layout)
    __shared__ short Bh[128 * 32];   // [col][k] 8 KB

    const int tid  = threadIdx.x;
    const int w    = tid >> 6;
    const int lane = tid & 63;
    const int ln   = lane & 15;
    const int qd   = lane >> 4;
    const int wr   = w >> 1, wc = w & 1;
    const int row0 = blockIdx.y * 128;
    const int col0 = blockIdx.x * 128;

    const int sr = lane >> 2;        // 0..15
    const int sk = (lane & 3) * 8;   // k element offset

    f32x4 acc[4][4];
#pragma unroll
    for (int mi = 0; mi < 4; mi++)
#pragma unroll
        for (int ni = 0; ni < 4; ni++)
            acc[mi][ni] = (f32x4){0.f, 0.f, 0.f, 0.f};

    for (int k0 = 0; k0 < K; k0 += 32) {
        __syncthreads();   // previous iter's frag reads done
#pragma unroll
        for (int t = 0; t < 2; t++) {
            const int rr = w * 32 + t * 16;      // chunk base row/col
            gload_lds16(A  + (size_t)(row0 + rr + sr) * lda + k0 + sk, &Ah[rr * 32]);
            gload_lds16(Bt + (size_t)(col0 + rr + sr) * K   + k0 + sk, &Bh[rr * 32]);
        }
        __syncthreads();   // vmcnt(0) drain inserted by compiler

        bf16x8 af[4], bf[4];
#pragma unroll
        for (int i = 0; i < 4; i++) {
            af[i] = *(const bf16x8*)&Ah[(wr * 64 + i * 16 + ln) * 32 + qd * 8];
            bf[i] = *(const bf16x8*)&Bh[(wc * 64 + i * 16 + ln) * 32 + qd * 8];
        }
#pragma unroll
        for (int mi = 0; mi < 4; mi++)
#pragma unroll
            for (int ni = 0; ni < 4; ni++)
                acc[mi][ni] = __builtin_amdgcn_mfma_f32_16x16x32_bf16(af[mi], bf[ni], acc[mi][ni], 0, 0, 0);
    }

    // epilogue: C(row0+wr*64+mi*16+qd*4+i, col0+wc*64+ni*16+ln)
#pragma unroll
    for (int mi = 0; mi < 4; mi++)
#pragma unroll
        for (int i = 0; i < 4; i++) {
            const size_t row = row0 + wr * 64 + mi * 16 + qd * 4 + i;
            if (OUT_BF16) {
                short* Cp = (short*)C + row * ldc + col0 + wc * 64 + ln;
#pragma unroll
                for (int ni = 0; ni < 4; ni++) Cp[ni * 16] = f2bf(acc[mi][ni][i]);
            } else {
                float* Cp = (float*)C + row * ldc + col0 + wc * 64 + ln;
#pragma unroll
                for (int ni = 0; ni < 4; ni++) Cp[ni * 16] = acc[mi][ni][i];
            }
        }
}

// ---------------------------------------------------------------------------
// RoPE in-place on bf16 qkv (token stride QKVW). 8 dims/thread.
// head 0..15 = q at col h*64; head 16..19 = k at col 1024+(h-16)*64.
// ---------------------------------------------------------------------------
__global__ __launch_bounds__(256) void rope_bf16(short* __restrict__ qkv,
                                                 const float* __restrict__ cosb,
                                                 const float* __restrict__ sinb) {
    int idx   = blockIdx.x * 256 + threadIdx.x;   // B*S*20*4 total
    int oct   = idx & 3;
    int head  = (idx >> 2) % 20;
    int token = idx / 80;
    int spos  = token % S_;
    int d0    = oct * 8;
    int coff  = (head < NH_) ? head * HD_ : H_ + (head - NH_) * HD_;

    short* p = qkv + (size_t)token * QKVW + coff;
    bf16x8 lo = *(bf16x8*)&p[d0];
    bf16x8 hi = *(bf16x8*)&p[d0 + 32];
    const float* cp = cosb + (size_t)spos * HD_;
    const float* sp = sinb + (size_t)spos * HD_;
    bf16x8 nlo, nhi;
#pragma unroll
    for (int j = 0; j < 8; j++) {
        float x0 = bf2f(lo[j]), x1 = bf2f(hi[j]);
        float c0 = cp[d0 + j], c1 = cp[d0 + 32 + j];
        float s0 = sp[d0 + j], s1 = sp[d0 + 32 + j];
        nlo[j] = f2bf(x0 * c0 - x1 * s0);
        nhi[j] = f2bf(x1 * c1 + x0 * s1);
    }
    *(bf16x8*)&p[d0]      = nlo;
    *(bf16x8*)&p[d0 + 32] = nhi;
}

// ---------------------------------------------------------------------------
// bf16 MFMA flash attention (v7 — 64-row blocks for 2x occupancy; V staged
// from the pre-transposed Vtg with coalesced b128 loads).
// grid = (S/64, B*NH) = 1024 blocks; block = 256 (4 waves x 16 q-rows).
// LDS 27.9 KB -> 4 blocks/CU resident (grid-limited), 16 waves/CU.
// Causal-balance: qt = (by&1) ? 31-bx : bx pairs heavy+light blocks.
// Output (bf16) overwrites the consumed q-slice of qkv (own rows/cols only).
// ---------------------------------------------------------------------------
__global__ __launch_bounds__(256) void attn_kernel(short* __restrict__ qkv,
                                                   const short* __restrict__ Vtg,
                                                   const float* __restrict__ maskb) {
    const int tid  = threadIdx.x;
    const int w    = tid >> 6;
    const int lane = tid & 63;
    const int ln   = lane & 15;
    const int qd   = lane >> 4;

    const int by = blockIdx.y;
    const int b  = by / NH_;
    const int h  = by % NH_;
    const int g  = h / R_;
    const int bg = b * NKV_ + g;
    const int qt = (by & 1) ? (31 - (int)blockIdx.x) : (int)blockIdx.x;
    const int q0 = qt * 64;
    const int rowb = q0 + w * 16;          // wave's first q-row

    __shared__ short Ks[64 * 72];          // K  [key][dim], stride 72 (9 KB)
    __shared__ short Vt[64 * 72];          // V^T [dim][key]            (9 KB)
    __shared__ short Ps[4 * 16 * 72];      // per-wave P [row][key]     (9 KB)
    __shared__ float mskS[64];

    // ---- Q A-frags: rows rowb+ln ----
    bf16x8 qf0, qf1;
    {
        const short* qp = qkv + (size_t)(b * S_ + rowb + ln) * QKVW + h * HD_;
        qf0 = *(const bf16x8*)&qp[qd * 8];
        qf1 = *(const bf16x8*)&qp[32 + qd * 8];
    }

    f32x4 O[4] = {};                       // [dt]: row=qd*4+i, dim=dt*16+ln
    float mrow[4], lrow[4];
#pragma unroll
    for (int i = 0; i < 4; i++) { mrow[i] = -1e30f; lrow[i] = 0.0f; }

    const int ktiles = qt + 1;
    for (int kt = 0; kt < ktiles; kt++) {
        const int base = kt * 64;

        // ---- stage K (coalesced b128 copies) ----
#pragma unroll
        for (int t = 0; t < 2; t++) {
            int flat = tid + t * 256;
            int key  = flat >> 3;
            int c8   = flat & 7;
            *(bf16x8*)&Ks[key * 72 + c8 * 8] =
                *(const bf16x8*)&qkv[(size_t)(b * S_ + base + key) * QKVW + H_ + g * HD_ + c8 * 8];
        }
        // ---- stage V^T from Vtg (coalesced b128 copies) ----
#pragma unroll
        for (int t = 0; t < 2; t++) {
            int flat = tid + t * 256;
            int d    = flat >> 3;
            int k8   = flat & 7;
            *(bf16x8*)&Vt[d * 72 + k8 * 8] =
                *(const bf16x8*)&Vtg[((size_t)bg * HD_ + d) * S_ + base + k8 * 8];
        }
        if (tid < 64) mskS[tid] = maskb[b * S_ + base + tid];
        __syncthreads();

        // ---- QK^T: S4[kg] (C-layout: row=qd*4+i, key=kg*16+ln) ----
        f32x4 S4[4];
#pragma unroll
        for (int kg = 0; kg < 4; kg++) {
            bf16x8 k0 = *(const bf16x8*)&Ks[(kg * 16 + ln) * 72 + qd * 8];
            bf16x8 k1 = *(const bf16x8*)&Ks[(kg * 16 + ln) * 72 + 32 + qd * 8];
            f32x4 z = {0.f, 0.f, 0.f, 0.f};
            z = __builtin_amdgcn_mfma_f32_16x16x32_bf16(qf0, k0, z, 0, 0, 0);
            S4[kg] = __builtin_amdgcn_mfma_f32_16x16x32_bf16(qf1, k1, z, 0, 0, 0);
        }

        // ---- online softmax + P write ----
        float mt[4];
#pragma unroll
        for (int kg = 0; kg < 4; kg++) mt[kg] = (1.0f - mskS[kg * 16 + ln]) * -1e9f;

        const int rb = rowb + qd * 4;
        float sc[4][4];
#pragma unroll
        for (int kg = 0; kg < 4; kg++) {
            const int key = base + kg * 16 + ln;
#pragma unroll
            for (int i = 0; i < 4; i++) {
                float v = S4[kg][i] * 0.125f + mt[kg];
                sc[kg][i] = (key <= rb + i) ? v : -1e30f;
            }
        }
#pragma unroll
        for (int i = 0; i < 4; i++) {
            float mx = fmaxf(fmaxf(sc[0][i], sc[1][i]), fmaxf(sc[2][i], sc[3][i]));
            mx = fmaxf(mx, __shfl_xor(mx, 1));
            mx = fmaxf(mx, __shfl_xor(mx, 2));
            mx = fmaxf(mx, __shfl_xor(mx, 4));
            mx = fmaxf(mx, __shfl_xor(mx, 8));
            float nm    = fmaxf(mrow[i], mx);
            float alpha = __expf(mrow[i] - nm);
            mrow[i] = nm;
            lrow[i] *= alpha;
#pragma unroll
            for (int dt = 0; dt < 4; dt++) O[dt][i] *= alpha;
        }
#pragma unroll
        for (int kg = 0; kg < 4; kg++)
#pragma unroll
            for (int i = 0; i < 4; i++) {
                float p = __expf(sc[kg][i] - mrow[i]);
                lrow[i] += p;
                Ps[w * 1152 + (qd * 4 + i) * 72 + kg * 16 + ln] = f2bf(p);
            }

        // ---- PV: O += P @ V ----
#pragma unroll
        for (int kc2 = 0; kc2 < 2; kc2++) {
            bf16x8 a0 = *(const bf16x8*)&Ps[w * 1152 + ln * 72 + kc2 * 32 + qd * 8];
#pragma unroll
            for (int dt = 0; dt < 4; dt++) {
                bf16x8 bv = *(const bf16x8*)&Vt[(dt * 16 + ln) * 72 + kc2 * 32 + qd * 8];
                O[dt] = __builtin_amdgcn_mfma_f32_16x16x32_bf16(a0, bv, O[dt], 0, 0, 0);
            }
        }
        __syncthreads();
    }

    // ---- finalize: reduce l across the 16 key-lanes, write bf16 q-slice ----
#pragma unroll
    for (int i = 0; i < 4; i++) {
        float l = lrow[i];
        l += __shfl_xor(l, 1);
        l += __shfl_xor(l, 2);
        l += __shfl_xor(l, 4);
        l += __shfl_xor(l, 8);
        float inv = 1.0f / l;
        const int row = rowb + qd * 4 + i;
        short* op = qkv + (size_t)(b * S_ + row) * QKVW + h * HD_ + ln;
#pragma unroll
        for (int dt = 0; dt < 4; dt++) op[dt * 16] = f2bf(O[dt][i] * inv);
    }
}

// ---------------------------------------------------------------------------
extern "C" void kernel_launch(void* const* d_in, const int* in_sizes, int n_in,
                              void* d_out, int out_size, void* d_ws, size_t ws_size,
                              hipStream_t stream) {
    const float* x     = (const float*)d_in[0];
    const float* cosb  = (const float*)d_in[1];
    const float* sinb  = (const float*)d_in[2];
    const float* maskb = (const float*)d_in[3];
    const float* Wq    = (const float*)d_in[4];
    const float* Wk    = (const float*)d_in[5];
    const float* Wv    = (const float*)d_in[6];
    const float* Wo    = (const float*)d_in[7];

    const int M = B_ * S_;   // 4096

    // xh (bf16 x) lives in d_out[0, 8MB) — consumed by GEMM1 before GEMM2
    // rewrites d_out.  ws: qkv | Wqkvt | Wot | Vtg  (19 MB bf16).
    short* xh    = (short*)d_out;
    short* qkv   = (short*)d_ws;                     // [4096][1536]
    short* Wqkvt = qkv + (size_t)M * QKVW;           // [1536][1024]
    short* Wot   = Wqkvt + (size_t)QKVW * H_;        // [1024][1024]
    short* Vtg   = Wot + (size_t)H_ * H_;            // [8*64][2048]
    float* out   = (float*)d_out;

    dim3 blk(256);

    convert_x<<<dim3((M * H_) / (8 * 256)), blk, 0, stream>>>(x, xh);

    tconv<<<dim3(H_ / 64, H_ / 64), blk, 0, stream>>>(Wq, Wqkvt, H_, H_);
    tconv<<<dim3((NKV_ * HD_) / 64, H_ / 64), blk, 0, stream>>>(Wk, Wqkvt + (size_t)H_ * H_, H_, NKV_ * HD_);
    tconv<<<dim3((NKV_ * HD_) / 64, H_ / 64), blk, 0, stream>>>(Wv, Wqkvt + (size_t)(H_ + NKV_ * HD_) * H_, H_, NKV_ * HD_);
    tconv<<<dim3(H_ / 64, H_ / 64), blk, 0, stream>>>(Wo, Wot, H_, H_);

    // GEMM1: qkv = xh @ Wqkvt^T  (bf16 out)
    gemm_bt_bf16<1><<<dim3(QKVW / 128, M / 128), blk, 0, stream>>>(xh, H_, Wqkvt, qkv, QKVW, H_);

    rope_bf16<<<dim3((M * 20 * 4) / 256), blk, 0, stream>>>(qkv, cosb, sinb);

    vtrans<<<dim3((B_ * NKV_ * HD_ * (S_ / 8)) / 256), blk, 0, stream>>>(qkv, Vtg);

    attn_kernel<<<dim3(S_ / 64, B_ * NH_), blk, 0, stream>>>(qkv, Vtg, maskb);

    // GEMM2: out = attn_out(q-slice of qkv, lda=1536) @ Wot^T  (fp32 out)
    gemm_bt_bf16<0><<<dim3(H_ / 128, M / 128), blk, 0, stream>>>(qkv, QKVW, Wot, out, H_, H_);
}

// Round 8
// 256.372 us; speedup vs baseline: 6.4949x; 1.0163x over previous
//
#include <hip/hip_runtime.h>
#include <math.h>

#define B_   2
#define S_   2048
#define H_   1024
#define NH_  16
#define NKV_ 4
#define HD_  64
#define R_   (NH_ / NKV_)   // 4 q-heads per kv-head
#define QKVW 1536           // qkv row width (q 0..1023 | k 1024..1279 | v 1280..1535)

typedef __attribute__((ext_vector_type(8))) short bf16x8;
typedef __attribute__((ext_vector_type(4))) float f32x4;

__device__ inline short f2bf(float f) {
    unsigned u = __float_as_uint(f);
    u += 0x7FFF + ((u >> 16) & 1);     // RNE to bf16
    return (short)(u >> 16);
}
__device__ inline float bf2f(short u) {
    return __uint_as_float(((unsigned)(unsigned short)u) << 16);
}

// async global->LDS, 16 B per lane; lptr is the wave-uniform chunk base,
// HW scatters lane i's 16 B at lptr + i*16 (m97/m104 semantics).
__device__ inline void gload_lds16(const void* gptr, void* lptr) {
    __builtin_amdgcn_global_load_lds(
        (const __attribute__((address_space(1))) unsigned int*)gptr,
        (__attribute__((address_space(3))) unsigned int*)lptr,
        16, 0, 0);
}

// ---------------------------------------------------------------------------
// x (fp32, row-major) -> bf16, elementwise. 8 elems/thread.
// ---------------------------------------------------------------------------
__global__ __launch_bounds__(256) void convert_x(const float* __restrict__ x,
                                                 short* __restrict__ xh) {
    int idx = blockIdx.x * 256 + threadIdx.x;
    const float4* xp = (const float4*)(x + (size_t)idx * 8);
    float4 a = xp[0], b = xp[1];
    bf16x8 o;
    o[0] = f2bf(a.x); o[1] = f2bf(a.y); o[2] = f2bf(a.z); o[3] = f2bf(a.w);
    o[4] = f2bf(b.x); o[5] = f2bf(b.y); o[6] = f2bf(b.z); o[7] = f2bf(b.w);
    *(bf16x8*)(xh + (size_t)idx * 8) = o;
}

// ---------------------------------------------------------------------------
// Wt[n][k] = bf16(W[k][n]); W is K x N fp32. 64x64 LDS-tiled transpose.
// ---------------------------------------------------------------------------
__global__ __launch_bounds__(256) void tconv(const float* __restrict__ W,
                                             short* __restrict__ Wt,
                                             int K, int N) {
    __shared__ short T[64][68];
    const int k0 = blockIdx.y * 64, n0 = blockIdx.x * 64;
    const int tid = threadIdx.x;
    const int r  = tid >> 4;
    const int c4 = (tid & 15) * 4;
#pragma unroll
    for (int t = 0; t < 4; t++) {
        int row = t * 16 + r;
        float4 v = *(const float4*)&W[(size_t)(k0 + row) * N + n0 + c4];
        T[c4 + 0][row] = f2bf(v.x);
        T[c4 + 1][row] = f2bf(v.y);
        T[c4 + 2][row] = f2bf(v.z);
        T[c4 + 3][row] = f2bf(v.w);
    }
    __syncthreads();
#pragma unroll
    for (int t = 0; t < 4; t++) {
        int row = t * 16 + r;          // n index
        short4 o = *(short4*)&T[row][c4];
        *(short4*)&Wt[(size_t)(n0 + row) * K + k0 + c4] = o;
    }
}

// ---------------------------------------------------------------------------
// V transpose pre-pass: Vtg[(b*NKV+g)*HD + d][s] = qkv v-slice (bf16).
// ---------------------------------------------------------------------------
__global__ __launch_bounds__(256) void vtrans(const short* __restrict__ qkv,
                                              short* __restrict__ Vtg) {
    int flat = blockIdx.x * 256 + threadIdx.x;
    int d  = flat & 63;
    int s8 = (flat >> 6) & (S_ / 8 - 1);
    int bg = flat >> 14;               // 0..7
    int b  = bg >> 2;
    int g  = bg & 3;
    const short* vp = qkv + ((size_t)(b * S_ + s8 * 8)) * QKVW + H_ + NKV_ * HD_ + g * HD_ + d;
    bf16x8 o;
#pragma unroll
    for (int j = 0; j < 8; j++) o[j] = vp[(size_t)j * QKVW];
    *(bf16x8*)&Vtg[((size_t)bg * HD_ + d) * S_ + s8 * 8] = o;
}

// ---------------------------------------------------------------------------
// bf16 MFMA GEMM, B^T form (m97 structure): C[M,N] = A[M,K] @ Bt[N,K]^T.
// 128x128 block tile, BK=32, 256 threads = 4 waves (2x2 of 64x64).
// ---------------------------------------------------------------------------
template <int OUT_BF16>
__global__ __launch_bounds__(256) void gemm_bt_bf16(const short* __restrict__ A, int lda,
                                                    const short* __restrict__ Bt,
                                                    void* __restrict__ C, int ldc,
                                                    int K) {
    __shared__ short Ah[128 * 32];   // [row][k] 8 KB, unpadded (glds layout)
    __shared__ short Bh[128 * 32];   // [col][k] 8 KB

    const int tid  = threadIdx.x;
    const int w    = tid >> 6;
    const int lane = tid & 63;
    const int ln   = lane & 15;
    const int qd   = lane >> 4;
    const int wr   = w >> 1, wc = w & 1;
    const int row0 = blockIdx.y * 128;
    const int col0 = blockIdx.x * 128;

    const int sr = lane >> 2;        // 0..15
    const int sk = (lane & 3) * 8;   // k element offset

    f32x4 acc[4][4];
#pragma unroll
    for (int mi = 0; mi < 4; mi++)
#pragma unroll
        for (int ni = 0; ni < 4; ni++)
            acc[mi][ni] = (f32x4){0.f, 0.f, 0.f, 0.f};

    for (int k0 = 0; k0 < K; k0 += 32) {
        __syncthreads();   // previous iter's frag reads done
#pragma unroll
        for (int t = 0; t < 2; t++) {
            const int rr = w * 32 + t * 16;      // chunk base row/col
            gload_lds16(A  + (size_t)(row0 + rr + sr) * lda + k0 + sk, &Ah[rr * 32]);
            gload_lds16(Bt + (size_t)(col0 + rr + sr) * K   + k0 + sk, &Bh[rr * 32]);
        }
        __syncthreads();   // vmcnt(0) drain inserted by compiler

        bf16x8 af[4], bf[4];
#pragma unroll
        for (int i = 0; i < 4; i++) {
            af[i] = *(const bf16x8*)&Ah[(wr * 64 + i * 16 + ln) * 32 + qd * 8];
            bf[i] = *(const bf16x8*)&Bh[(wc * 64 + i * 16 + ln) * 32 + qd * 8];
        }
#pragma unroll
        for (int mi = 0; mi < 4; mi++)
#pragma unroll
            for (int ni = 0; ni < 4; ni++)
                acc[mi][ni] = __builtin_amdgcn_mfma_f32_16x16x32_bf16(af[mi], bf[ni], acc[mi][ni], 0, 0, 0);
    }

#pragma unroll
    for (int mi = 0; mi < 4; mi++)
#pragma unroll
        for (int i = 0; i < 4; i++) {
            const size_t row = row0 + wr * 64 + mi * 16 + qd * 4 + i;
            if (OUT_BF16) {
                short* Cp = (short*)C + row * ldc + col0 + wc * 64 + ln;
#pragma unroll
                for (int ni = 0; ni < 4; ni++) Cp[ni * 16] = f2bf(acc[mi][ni][i]);
            } else {
                float* Cp = (float*)C + row * ldc + col0 + wc * 64 + ln;
#pragma unroll
                for (int ni = 0; ni < 4; ni++) Cp[ni * 16] = acc[mi][ni][i];
            }
        }
}

// ---------------------------------------------------------------------------
// RoPE in-place on bf16 qkv (token stride QKVW). 8 dims/thread.
// ---------------------------------------------------------------------------
__global__ __launch_bounds__(256) void rope_bf16(short* __restrict__ qkv,
                                                 const float* __restrict__ cosb,
                                                 const float* __restrict__ sinb) {
    int idx   = blockIdx.x * 256 + threadIdx.x;   // B*S*20*4 total
    int oct   = idx & 3;
    int head  = (idx >> 2) % 20;
    int token = idx / 80;
    int spos  = token % S_;
    int d0    = oct * 8;
    int coff  = (head < NH_) ? head * HD_ : H_ + (head - NH_) * HD_;

    short* p = qkv + (size_t)token * QKVW + coff;
    bf16x8 lo = *(bf16x8*)&p[d0];
    bf16x8 hi = *(bf16x8*)&p[d0 + 32];
    const float* cp = cosb + (size_t)spos * HD_;
    const float* sp = sinb + (size_t)spos * HD_;
    bf16x8 nlo, nhi;
#pragma unroll
    for (int j = 0; j < 8; j++) {
        float x0 = bf2f(lo[j]), x1 = bf2f(hi[j]);
        float c0 = cp[d0 + j], c1 = cp[d0 + 32 + j];
        float s0 = sp[d0 + j], s1 = sp[d0 + 32 + j];
        nlo[j] = f2bf(x0 * c0 - x1 * s0);
        nhi[j] = f2bf(x1 * c1 + x0 * s1);
    }
    *(bf16x8*)&p[d0]      = nlo;
    *(bf16x8*)&p[d0 + 32] = nhi;
}

// ---------------------------------------------------------------------------
// bf16 MFMA flash attention v8 — swapped-operand QK (S^T = K·Q^T).
// grid = (S/128, B*NH) = 512 blocks; block = 256 (4 waves x 32 q-rows,
// 2 row-groups of 16 per wave).
// Why swapped: K A-frags and V B-frags from LDS are shared across both
// row-groups (2x MFMA per DS read); S^T's C-layout puts 4 CONSECUTIVE
// keys of one q-row in each lane -> softmax reductions are 2-level shfl
// (xor 16/32), m/l are one scalar per rg, and P writes are 4 packed b64
// stores per rg (was 16 conflicting u16 stores).
// ---------------------------------------------------------------------------
__global__ __launch_bounds__(256) void attn_kernel(short* __restrict__ qkv,
                                                   const short* __restrict__ Vtg,
                                                   const float* __restrict__ maskb) {
    const int tid  = threadIdx.x;
    const int w    = tid >> 6;
    const int lane = tid & 63;
    const int ln   = lane & 15;
    const int qd   = lane >> 4;

    const int by = blockIdx.y;
    const int b  = by / NH_;
    const int h  = by % NH_;
    const int g  = h % NKV_ == h % NKV_ ? (h / R_) : 0;   // g = h / R_
    const int bg = b * NKV_ + (h / R_);
    const int qt = (by & 1) ? (15 - (int)blockIdx.x) : (int)blockIdx.x;
    const int q0 = qt * 128;
    const int rowb = q0 + w * 32;          // wave's first q-row

    __shared__ short Ks[64 * 72];          // K  [key][dim], stride 72 (9 KB)
    __shared__ short Vt[64 * 72];          // V^T [dim][key]            (9 KB)
    __shared__ short Ps[4 * 32 * 72];      // per-wave P [row 0..31][key] (18 KB)
    __shared__ float mskS[64];

    // ---- Q B-frags (B-layout == A-layout): rows rowb+rg*16+ln ----
    bf16x8 qf[2][2];
#pragma unroll
    for (int rg = 0; rg < 2; rg++) {
        const short* qp = qkv + (size_t)(b * S_ + rowb + rg * 16 + ln) * QKVW + h * HD_;
        qf[rg][0] = *(const bf16x8*)&qp[qd * 8];
        qf[rg][1] = *(const bf16x8*)&qp[32 + qd * 8];
    }

    f32x4 O[2][4] = {};                    // [rg][dt]: row=qd*4+i, dim=dt*16+ln
    float mrow[2] = {-1e30f, -1e30f};      // per-rg, row = ln (replicated over qd)
    float lrow[2] = {0.0f, 0.0f};

    const int ktiles = 2 * qt + 2;
    for (int kt = 0; kt < ktiles; kt++) {
        const int base = kt * 64;

        // ---- stage K (coalesced b128 copies) ----
#pragma unroll
        for (int t = 0; t < 2; t++) {
            int flat = tid + t * 256;
            int key  = flat >> 3;
            int c8   = flat & 7;
            *(bf16x8*)&Ks[key * 72 + c8 * 8] =
                *(const bf16x8*)&qkv[(size_t)(b * S_ + base + key) * QKVW + H_ + (h / R_) * HD_ + c8 * 8];
        }
        // ---- stage V^T from Vtg (coalesced b128 copies) ----
#pragma unroll
        for (int t = 0; t < 2; t++) {
            int flat = tid + t * 256;
            int d    = flat >> 3;
            int k8   = flat & 7;
            *(bf16x8*)&Vt[d * 72 + k8 * 8] =
                *(const bf16x8*)&Vtg[((size_t)bg * HD_ + d) * S_ + base + k8 * 8];
        }
        if (tid < 64) mskS[tid] = maskb[b * S_ + base + tid];
        __syncthreads();

        // ---- QK^T swapped: St[rg][kg] = S^T tile.
        // Lane (qd,ln) reg i holds S[row=rowb+rg*16+ln][key=base+kg*16+qd*4+i].
        f32x4 St[2][4];
#pragma unroll
        for (int kg = 0; kg < 4; kg++) {
            bf16x8 ka0 = *(const bf16x8*)&Ks[(kg * 16 + ln) * 72 + qd * 8];
            bf16x8 ka1 = *(const bf16x8*)&Ks[(kg * 16 + ln) * 72 + 32 + qd * 8];
#pragma unroll
            for (int rg = 0; rg < 2; rg++) {
                f32x4 z = {0.f, 0.f, 0.f, 0.f};
                z = __builtin_amdgcn_mfma_f32_16x16x32_bf16(ka0, qf[rg][0], z, 0, 0, 0);
                St[rg][kg] = __builtin_amdgcn_mfma_f32_16x16x32_bf16(ka1, qf[rg][1], z, 0, 0, 0);
            }
        }

        // ---- per-lane mask bias for keys base+kg*16+qd*4+i ----
        float mt[4][4];
#pragma unroll
        for (int kg = 0; kg < 4; kg++) {
            float4 mv = *(const float4*)&mskS[kg * 16 + qd * 4];
            mt[kg][0] = (1.0f - mv.x) * -1e9f;
            mt[kg][1] = (1.0f - mv.y) * -1e9f;
            mt[kg][2] = (1.0f - mv.z) * -1e9f;
            mt[kg][3] = (1.0f - mv.w) * -1e9f;
        }

        // ---- online softmax per rg (row = ln) + packed P write ----
#pragma unroll
        for (int rg = 0; rg < 2; rg++) {
            const int qrow = rowb + rg * 16 + ln;
            float sc[4][4];
#pragma unroll
            for (int kg = 0; kg < 4; kg++) {
                const int keyb = base + kg * 16 + qd * 4;
#pragma unroll
                for (int i = 0; i < 4; i++) {
                    float v = St[rg][kg][i] * 0.125f + mt[kg][i];
                    sc[kg][i] = (keyb + i <= qrow) ? v : -1e30f;
                }
            }
            float mx = sc[0][0];
#pragma unroll
            for (int kg = 0; kg < 4; kg++)
#pragma unroll
                for (int i = 0; i < 4; i++) mx = fmaxf(mx, sc[kg][i]);
            mx = fmaxf(mx, __shfl_xor(mx, 16));
            mx = fmaxf(mx, __shfl_xor(mx, 32));

            float nm    = fmaxf(mrow[rg], mx);
            float alpha = __expf(mrow[rg] - nm);
            mrow[rg] = nm;

            float ls = 0.0f;
            float pr[4][4];
#pragma unroll
            for (int kg = 0; kg < 4; kg++)
#pragma unroll
                for (int i = 0; i < 4; i++) {
                    float p = __expf(sc[kg][i] - nm);
                    pr[kg][i] = p;
                    ls += p;
                }
            ls += __shfl_xor(ls, 16);
            ls += __shfl_xor(ls, 32);
            lrow[rg] = lrow[rg] * alpha + ls;

            // rescale O (rows qd*4+i): broadcast alpha from lane qd*4+i
#pragma unroll
            for (int i = 0; i < 4; i++) {
                float av = __shfl(alpha, qd * 4 + i);
#pragma unroll
                for (int dt = 0; dt < 4; dt++) O[rg][dt][i] *= av;
            }

            // packed P write: 4 consecutive keys per lane per kg -> b64
#pragma unroll
            for (int kg = 0; kg < 4; kg++) {
                short4 pk = { f2bf(pr[kg][0]), f2bf(pr[kg][1]),
                              f2bf(pr[kg][2]), f2bf(pr[kg][3]) };
                *(short4*)&Ps[w * 2304 + (rg * 16 + ln) * 72 + kg * 16 + qd * 4] = pk;
            }
        }

        // ---- PV: O[rg] += P[rg] @ V ; V B-frags shared across rgs ----
#pragma unroll
        for (int kc2 = 0; kc2 < 2; kc2++) {
            bf16x8 pa0 = *(const bf16x8*)&Ps[w * 2304 + (ln)      * 72 + kc2 * 32 + qd * 8];
            bf16x8 pa1 = *(const bf16x8*)&Ps[w * 2304 + (16 + ln) * 72 + kc2 * 32 + qd * 8];
#pragma unroll
            for (int dt = 0; dt < 4; dt++) {
                bf16x8 vb = *(const bf16x8*)&Vt[(dt * 16 + ln) * 72 + kc2 * 32 + qd * 8];
                O[0][dt] = __builtin_amdgcn_mfma_f32_16x16x32_bf16(pa0, vb, O[0][dt], 0, 0, 0);
                O[1][dt] = __builtin_amdgcn_mfma_f32_16x16x32_bf16(pa1, vb, O[1][dt], 0, 0, 0);
            }
        }
        __syncthreads();
    }

    // ---- finalize: l is already the full row sum (replicated over qd) ----
#pragma unroll
    for (int rg = 0; rg < 2; rg++)
#pragma unroll
        for (int i = 0; i < 4; i++) {
            float li  = __shfl(lrow[rg], qd * 4 + i);
            float inv = 1.0f / li;
            const int row = rowb + rg * 16 + qd * 4 + i;
            short* op = qkv + (size_t)(b * S_ + row) * QKVW + h * HD_ + ln;
#pragma unroll
            for (int dt = 0; dt < 4; dt++) op[dt * 16] = f2bf(O[rg][dt][i] * inv);
        }
}

// ---------------------------------------------------------------------------
extern "C" void kernel_launch(void* const* d_in, const int* in_sizes, int n_in,
                              void* d_out, int out_size, void* d_ws, size_t ws_size,
                              hipStream_t stream) {
    const float* x     = (const float*)d_in[0];
    const float* cosb  = (const float*)d_in[1];
    const float* sinb  = (const float*)d_in[2];
    const float* maskb = (const float*)d_in[3];
    const float* Wq    = (const float*)d_in[4];
    const float* Wk    = (const float*)d_in[5];
    const float* Wv    = (const float*)d_in[6];
    const float* Wo    = (const float*)d_in[7];

    const int M = B_ * S_;   // 4096

    // xh (bf16 x) lives in d_out[0, 8MB) — consumed by GEMM1 before GEMM2
    // rewrites d_out.  ws: qkv | Wqkvt | Wot | Vtg  (19 MB bf16).
    short* xh    = (short*)d_out;
    short* qkv   = (short*)d_ws;                     // [4096][1536]
    short* Wqkvt = qkv + (size_t)M * QKVW;           // [1536][1024]
    short* Wot   = Wqkvt + (size_t)QKVW * H_;        // [1024][1024]
    short* Vtg   = Wot + (size_t)H_ * H_;            // [8*64][2048]
    float* out   = (float*)d_out;

    dim3 blk(256);

    convert_x<<<dim3((M * H_) / (8 * 256)), blk, 0, stream>>>(x, xh);

    tconv<<<dim3(H_ / 64, H_ / 64), blk, 0, stream>>>(Wq, Wqkvt, H_, H_);
    tconv<<<dim3((NKV_ * HD_) / 64, H_ / 64), blk, 0, stream>>>(Wk, Wqkvt + (size_t)H_ * H_, H_, NKV_ * HD_);
    tconv<<<dim3((NKV_ * HD_) / 64, H_ / 64), blk, 0, stream>>>(Wv, Wqkvt + (size_t)(H_ + NKV_ * HD_) * H_, H_, NKV_ * HD_);
    tconv<<<dim3(H_ / 64, H_ / 64), blk, 0, stream>>>(Wo, Wot, H_, H_);

    // GEMM1: qkv = xh @ Wqkvt^T  (bf16 out)
    gemm_bt_bf16<1><<<dim3(QKVW / 128, M / 128), blk, 0, stream>>>(xh, H_, Wqkvt, qkv, QKVW, H_);

    rope_bf16<<<dim3((M * 20 * 4) / 256), blk, 0, stream>>>(qkv, cosb, sinb);

    vtrans<<<dim3((B_ * NKV_ * HD_ * (S_ / 8)) / 256), blk, 0, stream>>>(qkv, Vtg);

    attn_kernel<<<dim3(S_ / 128, B_ * NH_), blk, 0, stream>>>(qkv, Vtg, maskb);

    // GEMM2: out = attn_out(q-slice of qkv, lda=1536) @ Wot^T  (fp32 out)
    gemm_bt_bf16<0><<<dim3(H_ / 128, M / 128), blk, 0, stream>>>(qkv, QKVW, Wot, out, H_, H_);
}

// Round 9
// 252.286 us; speedup vs baseline: 6.6001x; 1.0162x over previous
//
#include <hip/hip_runtime.h>
#include <math.h>

#define B_   2
#define S_   2048
#define H_   1024
#define NH_  16
#define NKV_ 4
#define HD_  64
#define R_   (NH_ / NKV_)   // 4 q-heads per kv-head
#define QKVW 1536           // qkv row width (q 0..1023 | k 1024..1279 | v 1280..1535)

typedef __attribute__((ext_vector_type(8))) short bf16x8;
typedef __attribute__((ext_vector_type(4))) float f32x4;

__device__ inline short f2bf(float f) {
    unsigned u = __float_as_uint(f);
    u += 0x7FFF + ((u >> 16) & 1);     // RNE to bf16
    return (short)(u >> 16);
}
__device__ inline float bf2f(short u) {
    return __uint_as_float(((unsigned)(unsigned short)u) << 16);
}

// async global->LDS, 16 B per lane; lptr is the wave-uniform chunk base,
// HW scatters lane i's 16 B at lptr + i*16 (m97/m104 semantics).
__device__ inline void gload_lds16(const void* gptr, void* lptr) {
    __builtin_amdgcn_global_load_lds(
        (const __attribute__((address_space(1))) unsigned int*)gptr,
        (__attribute__((address_space(3))) unsigned int*)lptr,
        16, 0, 0);
}

// ---------------------------------------------------------------------------
// x (fp32, row-major) -> bf16, elementwise. 8 elems/thread.
// ---------------------------------------------------------------------------
__global__ __launch_bounds__(256) void convert_x(const float* __restrict__ x,
                                                 short* __restrict__ xh) {
    int idx = blockIdx.x * 256 + threadIdx.x;
    const float4* xp = (const float4*)(x + (size_t)idx * 8);
    float4 a = xp[0], b = xp[1];
    bf16x8 o;
    o[0] = f2bf(a.x); o[1] = f2bf(a.y); o[2] = f2bf(a.z); o[3] = f2bf(a.w);
    o[4] = f2bf(b.x); o[5] = f2bf(b.y); o[6] = f2bf(b.z); o[7] = f2bf(b.w);
    *(bf16x8*)(xh + (size_t)idx * 8) = o;
}

// ---------------------------------------------------------------------------
// Wt[n][k] = bf16(W[k][n]); W is K x N fp32. 64x64 LDS-tiled transpose.
// ---------------------------------------------------------------------------
__global__ __launch_bounds__(256) void tconv(const float* __restrict__ W,
                                             short* __restrict__ Wt,
                                             int K, int N) {
    __shared__ short T[64][68];
    const int k0 = blockIdx.y * 64, n0 = blockIdx.x * 64;
    const int tid = threadIdx.x;
    const int r  = tid >> 4;
    const int c4 = (tid & 15) * 4;
#pragma unroll
    for (int t = 0; t < 4; t++) {
        int row = t * 16 + r;
        float4 v = *(const float4*)&W[(size_t)(k0 + row) * N + n0 + c4];
        T[c4 + 0][row] = f2bf(v.x);
        T[c4 + 1][row] = f2bf(v.y);
        T[c4 + 2][row] = f2bf(v.z);
        T[c4 + 3][row] = f2bf(v.w);
    }
    __syncthreads();
#pragma unroll
    for (int t = 0; t < 4; t++) {
        int row = t * 16 + r;          // n index
        short4 o = *(short4*)&T[row][c4];
        *(short4*)&Wt[(size_t)(n0 + row) * K + k0 + c4] = o;
    }
}

// ---------------------------------------------------------------------------
// V transpose pre-pass: Vtg[(b*NKV+g)*HD + d][s] = qkv v-slice (bf16).
// ---------------------------------------------------------------------------
__global__ __launch_bounds__(256) void vtrans(const short* __restrict__ qkv,
                                              short* __restrict__ Vtg) {
    int flat = blockIdx.x * 256 + threadIdx.x;
    int d  = flat & 63;
    int s8 = (flat >> 6) & (S_ / 8 - 1);
    int bg = flat >> 14;               // 0..7
    int b  = bg >> 2;
    int g  = bg & 3;
    const short* vp = qkv + ((size_t)(b * S_ + s8 * 8)) * QKVW + H_ + NKV_ * HD_ + g * HD_ + d;
    bf16x8 o;
#pragma unroll
    for (int j = 0; j < 8; j++) o[j] = vp[(size_t)j * QKVW];
    *(bf16x8*)&Vtg[((size_t)bg * HD_ + d) * S_ + s8 * 8] = o;
}

// ---------------------------------------------------------------------------
// bf16 MFMA GEMM, B^T form (m97 structure): C[M,N] = A[M,K] @ Bt[N,K]^T.
// 128x128 block tile, BK=32, 256 threads = 4 waves (2x2 of 64x64).
// ---------------------------------------------------------------------------
template <int OUT_BF16>
__global__ __launch_bounds__(256) void gemm_bt_bf16(const short* __restrict__ A, int lda,
                                                    const short* __restrict__ Bt,
                                                    void* __restrict__ C, int ldc,
                                                    int K) {
    __shared__ short Ah[128 * 32];   // [row][k] 8 KB, unpadded (glds layout)
    __shared__ short Bh[128 * 32];   // [col][k] 8 KB

    const int tid  = threadIdx.x;
    const int w    = tid >> 6;
    const int lane = tid & 63;
    const int ln   = lane & 15;
    const int qd   = lane >> 4;
    const int wr   = w >> 1, wc = w & 1;
    const int row0 = blockIdx.y * 128;
    const int col0 = blockIdx.x * 128;

    const int sr = lane >> 2;        // 0..15
    const int sk = (lane & 3) * 8;   // k element offset

    f32x4 acc[4][4];
#pragma unroll
    for (int mi = 0; mi < 4; mi++)
#pragma unroll
        for (int ni = 0; ni < 4; ni++)
            acc[mi][ni] = (f32x4){0.f, 0.f, 0.f, 0.f};

    for (int k0 = 0; k0 < K; k0 += 32) {
        __syncthreads();   // previous iter's frag reads done
#pragma unroll
        for (int t = 0; t < 2; t++) {
            const int rr = w * 32 + t * 16;      // chunk base row/col
            gload_lds16(A  + (size_t)(row0 + rr + sr) * lda + k0 + sk, &Ah[rr * 32]);
            gload_lds16(Bt + (size_t)(col0 + rr + sr) * K   + k0 + sk, &Bh[rr * 32]);
        }
        __syncthreads();   // vmcnt(0) drain inserted by compiler

        bf16x8 af[4], bf[4];
#pragma unroll
        for (int i = 0; i < 4; i++) {
            af[i] = *(const bf16x8*)&Ah[(wr * 64 + i * 16 + ln) * 32 + qd * 8];
            bf[i] = *(const bf16x8*)&Bh[(wc * 64 + i * 16 + ln) * 32 + qd * 8];
        }
#pragma unroll
        for (int mi = 0; mi < 4; mi++)
#pragma unroll
            for (int ni = 0; ni < 4; ni++)
                acc[mi][ni] = __builtin_amdgcn_mfma_f32_16x16x32_bf16(af[mi], bf[ni], acc[mi][ni], 0, 0, 0);
    }

#pragma unroll
    for (int mi = 0; mi < 4; mi++)
#pragma unroll
        for (int i = 0; i < 4; i++) {
            const size_t row = row0 + wr * 64 + mi * 16 + qd * 4 + i;
            if (OUT_BF16) {
                short* Cp = (short*)C + row * ldc + col0 + wc * 64 + ln;
#pragma unroll
                for (int ni = 0; ni < 4; ni++) Cp[ni * 16] = f2bf(acc[mi][ni][i]);
            } else {
                float* Cp = (float*)C + row * ldc + col0 + wc * 64 + ln;
#pragma unroll
                for (int ni = 0; ni < 4; ni++) Cp[ni * 16] = acc[mi][ni][i];
            }
        }
}

// ---------------------------------------------------------------------------
// RoPE in-place on bf16 qkv (token stride QKVW). 8 dims/thread.
// ---------------------------------------------------------------------------
__global__ __launch_bounds__(256) void rope_bf16(short* __restrict__ qkv,
                                                 const float* __restrict__ cosb,
                                                 const float* __restrict__ sinb) {
    int idx   = blockIdx.x * 256 + threadIdx.x;   // B*S*20*4 total
    int oct   = idx & 3;
    int head  = (idx >> 2) % 20;
    int token = idx / 80;
    int spos  = token % S_;
    int d0    = oct * 8;
    int coff  = (head < NH_) ? head * HD_ : H_ + (head - NH_) * HD_;

    short* p = qkv + (size_t)token * QKVW + coff;
    bf16x8 lo = *(bf16x8*)&p[d0];
    bf16x8 hi = *(bf16x8*)&p[d0 + 32];
    const float* cp = cosb + (size_t)spos * HD_;
    const float* sp = sinb + (size_t)spos * HD_;
    bf16x8 nlo, nhi;
#pragma unroll
    for (int j = 0; j < 8; j++) {
        float x0 = bf2f(lo[j]), x1 = bf2f(hi[j]);
        float c0 = cp[d0 + j], c1 = cp[d0 + 32 + j];
        float s0 = sp[d0 + j], s1 = sp[d0 + 32 + j];
        nlo[j] = f2bf(x0 * c0 - x1 * s0);
        nhi[j] = f2bf(x1 * c1 + x0 * s1);
    }
    *(bf16x8*)&p[d0]      = nlo;
    *(bf16x8*)&p[d0 + 32] = nhi;
}

// ---------------------------------------------------------------------------
// bf16 MFMA flash attention v9 — v8 (swapped-operand QK) + double-buffered
// K/V staging: prefetch tile kt+1 into registers right after the barrier,
// compute on buffer cur, write prefetch to cur^1, ONE barrier per tile.
// Staging latency overlaps compute instead of serializing with it.
// grid = (S/128, B*NH) = 512 blocks; block = 256 (4 waves x 32 q-rows).
// LDS 55.7 KB -> 2 blocks/CU (matches 2 blocks/CU grid).
// ---------------------------------------------------------------------------
__global__ __launch_bounds__(256) void attn_kernel(short* __restrict__ qkv,
                                                   const short* __restrict__ Vtg,
                                                   const float* __restrict__ maskb) {
    const int tid  = threadIdx.x;
    const int w    = tid >> 6;
    const int lane = tid & 63;
    const int ln   = lane & 15;
    const int qd   = lane >> 4;

    const int by = blockIdx.y;
    const int b  = by / NH_;
    const int h  = by % NH_;
    const int g  = h / R_;
    const int bg = b * NKV_ + g;
    const int qt = (by & 1) ? (15 - (int)blockIdx.x) : (int)blockIdx.x;
    const int q0 = qt * 128;
    const int rowb = q0 + w * 32;          // wave's first q-row

    __shared__ short Ks[2][64 * 72];       // K  [key][dim], stride 72 (2x9 KB)
    __shared__ short Vt[2][64 * 72];       // V^T [dim][key]            (2x9 KB)
    __shared__ short Ps[4 * 32 * 72];      // per-wave P [row 0..31][key] (18 KB)
    __shared__ float mskS[2][64];

    // staging coordinates (same for K and V loops)
    const int f0r = tid >> 3,        f0c = (tid & 7) * 8;          // t=0
    const int f1r = (tid + 256) >> 3, f1c = ((tid + 256) & 7) * 8; // t=1

    // ---- Q B-frags (B-layout == A-layout): rows rowb+rg*16+ln ----
    bf16x8 qf[2][2];
#pragma unroll
    for (int rg = 0; rg < 2; rg++) {
        const short* qp = qkv + (size_t)(b * S_ + rowb + rg * 16 + ln) * QKVW + h * HD_;
        qf[rg][0] = *(const bf16x8*)&qp[qd * 8];
        qf[rg][1] = *(const bf16x8*)&qp[32 + qd * 8];
    }

    f32x4 O[2][4] = {};                    // [rg][dt]: row=qd*4+i, dim=dt*16+ln
    float mrow[2] = {-1e30f, -1e30f};      // per-rg, row = ln (replicated over qd)
    float lrow[2] = {0.0f, 0.0f};

    const int ktiles = 2 * qt + 2;

    // ---- stage tile 0 into buffer 0 ----
    {
        *(bf16x8*)&Ks[0][f0r * 72 + f0c] =
            *(const bf16x8*)&qkv[(size_t)(b * S_ + f0r) * QKVW + H_ + g * HD_ + f0c];
        *(bf16x8*)&Ks[0][f1r * 72 + f1c] =
            *(const bf16x8*)&qkv[(size_t)(b * S_ + f1r) * QKVW + H_ + g * HD_ + f1c];
        *(bf16x8*)&Vt[0][f0r * 72 + f0c] =
            *(const bf16x8*)&Vtg[((size_t)bg * HD_ + f0r) * S_ + f0c];
        *(bf16x8*)&Vt[0][f1r * 72 + f1c] =
            *(const bf16x8*)&Vtg[((size_t)bg * HD_ + f1r) * S_ + f1c];
        if (tid < 64) mskS[0][tid] = maskb[b * S_ + tid];
    }
    __syncthreads();

    int cur = 0;
    for (int kt = 0; kt < ktiles; kt++) {
        const int base = kt * 64;
        const bool pf = (kt + 1 < ktiles);

        // ---- prefetch tile kt+1 into registers (no wait) ----
        bf16x8 pk0, pk1, pv0, pv1;
        float pm = 0.0f;
        if (pf) {
            const int nb = base + 64;
            pk0 = *(const bf16x8*)&qkv[(size_t)(b * S_ + nb + f0r) * QKVW + H_ + g * HD_ + f0c];
            pk1 = *(const bf16x8*)&qkv[(size_t)(b * S_ + nb + f1r) * QKVW + H_ + g * HD_ + f1c];
            pv0 = *(const bf16x8*)&Vtg[((size_t)bg * HD_ + f0r) * S_ + nb + f0c];
            pv1 = *(const bf16x8*)&Vtg[((size_t)bg * HD_ + f1r) * S_ + nb + f1c];
            if (tid < 64) pm = maskb[b * S_ + nb + tid];
        }

        // ---- QK^T swapped: St[rg][kg] = S^T tile.
        // Lane (qd,ln) reg i holds S[row=rowb+rg*16+ln][key=base+kg*16+qd*4+i].
        f32x4 St[2][4];
#pragma unroll
        for (int kg = 0; kg < 4; kg++) {
            bf16x8 ka0 = *(const bf16x8*)&Ks[cur][(kg * 16 + ln) * 72 + qd * 8];
            bf16x8 ka1 = *(const bf16x8*)&Ks[cur][(kg * 16 + ln) * 72 + 32 + qd * 8];
#pragma unroll
            for (int rg = 0; rg < 2; rg++) {
                f32x4 z = {0.f, 0.f, 0.f, 0.f};
                z = __builtin_amdgcn_mfma_f32_16x16x32_bf16(ka0, qf[rg][0], z, 0, 0, 0);
                St[rg][kg] = __builtin_amdgcn_mfma_f32_16x16x32_bf16(ka1, qf[rg][1], z, 0, 0, 0);
            }
        }

        // ---- per-lane mask bias for keys base+kg*16+qd*4+i ----
        float mt[4][4];
#pragma unroll
        for (int kg = 0; kg < 4; kg++) {
            float4 mv = *(const float4*)&mskS[cur][kg * 16 + qd * 4];
            mt[kg][0] = (1.0f - mv.x) * -1e9f;
            mt[kg][1] = (1.0f - mv.y) * -1e9f;
            mt[kg][2] = (1.0f - mv.z) * -1e9f;
            mt[kg][3] = (1.0f - mv.w) * -1e9f;
        }

        // ---- online softmax per rg (row = ln) + packed P write ----
#pragma unroll
        for (int rg = 0; rg < 2; rg++) {
            const int qrow = rowb + rg * 16 + ln;
            float sc[4][4];
#pragma unroll
            for (int kg = 0; kg < 4; kg++) {
                const int keyb = base + kg * 16 + qd * 4;
#pragma unroll
                for (int i = 0; i < 4; i++) {
                    float v = St[rg][kg][i] * 0.125f + mt[kg][i];
                    sc[kg][i] = (keyb + i <= qrow) ? v : -1e30f;
                }
            }
            float mx = sc[0][0];
#pragma unroll
            for (int kg = 0; kg < 4; kg++)
#pragma unroll
                for (int i = 0; i < 4; i++) mx = fmaxf(mx, sc[kg][i]);
            mx = fmaxf(mx, __shfl_xor(mx, 16));
            mx = fmaxf(mx, __shfl_xor(mx, 32));

            float nm    = fmaxf(mrow[rg], mx);
            float alpha = __expf(mrow[rg] - nm);
            mrow[rg] = nm;

            float ls = 0.0f;
            float pr[4][4];
#pragma unroll
            for (int kg = 0; kg < 4; kg++)
#pragma unroll
                for (int i = 0; i < 4; i++) {
                    float p = __expf(sc[kg][i] - nm);
                    pr[kg][i] = p;
                    ls += p;
                }
            ls += __shfl_xor(ls, 16);
            ls += __shfl_xor(ls, 32);
            lrow[rg] = lrow[rg] * alpha + ls;

            // rescale O (rows qd*4+i): broadcast alpha from lane qd*4+i
#pragma unroll
            for (int i = 0; i < 4; i++) {
                float av = __shfl(alpha, qd * 4 + i);
#pragma unroll
                for (int dt = 0; dt < 4; dt++) O[rg][dt][i] *= av;
            }

            // packed P write: 4 consecutive keys per lane per kg -> b64
#pragma unroll
            for (int kg = 0; kg < 4; kg++) {
                short4 pk = { f2bf(pr[kg][0]), f2bf(pr[kg][1]),
                              f2bf(pr[kg][2]), f2bf(pr[kg][3]) };
                *(short4*)&Ps[w * 2304 + (rg * 16 + ln) * 72 + kg * 16 + qd * 4] = pk;
            }
        }

        // ---- PV: O[rg] += P[rg] @ V ; V B-frags shared across rgs ----
#pragma unroll
        for (int kc2 = 0; kc2 < 2; kc2++) {
            bf16x8 pa0 = *(const bf16x8*)&Ps[w * 2304 + (ln)      * 72 + kc2 * 32 + qd * 8];
            bf16x8 pa1 = *(const bf16x8*)&Ps[w * 2304 + (16 + ln) * 72 + kc2 * 32 + qd * 8];
#pragma unroll
            for (int dt = 0; dt < 4; dt++) {
                bf16x8 vb = *(const bf16x8*)&Vt[cur][(dt * 16 + ln) * 72 + kc2 * 32 + qd * 8];
                O[0][dt] = __builtin_amdgcn_mfma_f32_16x16x32_bf16(pa0, vb, O[0][dt], 0, 0, 0);
                O[1][dt] = __builtin_amdgcn_mfma_f32_16x16x32_bf16(pa1, vb, O[1][dt], 0, 0, 0);
            }
        }

        // ---- write prefetched tile into the other buffer ----
        if (pf) {
            const int nxt = cur ^ 1;
            *(bf16x8*)&Ks[nxt][f0r * 72 + f0c] = pk0;
            *(bf16x8*)&Ks[nxt][f1r * 72 + f1c] = pk1;
            *(bf16x8*)&Vt[nxt][f0r * 72 + f0c] = pv0;
            *(bf16x8*)&Vt[nxt][f1r * 72 + f1c] = pv1;
            if (tid < 64) mskS[nxt][tid] = pm;
        }
        __syncthreads();
        cur ^= 1;
    }

    // ---- finalize: l is already the full row sum (replicated over qd) ----
#pragma unroll
    for (int rg = 0; rg < 2; rg++)
#pragma unroll
        for (int i = 0; i < 4; i++) {
            float li  = __shfl(lrow[rg], qd * 4 + i);
            float inv = 1.0f / li;
            const int row = rowb + rg * 16 + qd * 4 + i;
            short* op = qkv + (size_t)(b * S_ + row) * QKVW + h * HD_ + ln;
#pragma unroll
            for (int dt = 0; dt < 4; dt++) op[dt * 16] = f2bf(O[rg][dt][i] * inv);
        }
}

// ---------------------------------------------------------------------------
extern "C" void kernel_launch(void* const* d_in, const int* in_sizes, int n_in,
                              void* d_out, int out_size, void* d_ws, size_t ws_size,
                              hipStream_t stream) {
    const float* x     = (const float*)d_in[0];
    const float* cosb  = (const float*)d_in[1];
    const float* sinb  = (const float*)d_in[2];
    const float* maskb = (const float*)d_in[3];
    const float* Wq    = (const float*)d_in[4];
    const float* Wk    = (const float*)d_in[5];
    const float* Wv    = (const float*)d_in[6];
    const float* Wo    = (const float*)d_in[7];

    const int M = B_ * S_;   // 4096

    // xh (bf16 x) lives in d_out[0, 8MB) — consumed by GEMM1 before GEMM2
    // rewrites d_out.  ws: qkv | Wqkvt | Wot | Vtg  (19 MB bf16).
    short* xh    = (short*)d_out;
    short* qkv   = (short*)d_ws;                     // [4096][1536]
    short* Wqkvt = qkv + (size_t)M * QKVW;           // [1536][1024]
    short* Wot   = Wqkvt + (size_t)QKVW * H_;        // [1024][1024]
    short* Vtg   = Wot + (size_t)H_ * H_;            // [8*64][2048]
    float* out   = (float*)d_out;

    dim3 blk(256);

    convert_x<<<dim3((M * H_) / (8 * 256)), blk, 0, stream>>>(x, xh);

    tconv<<<dim3(H_ / 64, H_ / 64), blk, 0, stream>>>(Wq, Wqkvt, H_, H_);
    tconv<<<dim3((NKV_ * HD_) / 64, H_ / 64), blk, 0, stream>>>(Wk, Wqkvt + (size_t)H_ * H_, H_, NKV_ * HD_);
    tconv<<<dim3((NKV_ * HD_) / 64, H_ / 64), blk, 0, stream>>>(Wv, Wqkvt + (size_t)(H_ + NKV_ * HD_) * H_, H_, NKV_ * HD_);
    tconv<<<dim3(H_ / 64, H_ / 64), blk, 0, stream>>>(Wo, Wot, H_, H_);

    // GEMM1: qkv = xh @ Wqkvt^T  (bf16 out)
    gemm_bt_bf16<1><<<dim3(QKVW / 128, M / 128), blk, 0, stream>>>(xh, H_, Wqkvt, qkv, QKVW, H_);

    rope_bf16<<<dim3((M * 20 * 4) / 256), blk, 0, stream>>>(qkv, cosb, sinb);

    vtrans<<<dim3((B_ * NKV_ * HD_ * (S_ / 8)) / 256), blk, 0, stream>>>(qkv, Vtg);

    attn_kernel<<<dim3(S_ / 128, B_ * NH_), blk, 0, stream>>>(qkv, Vtg, maskb);

    // GEMM2: out = attn_out(q-slice of qkv, lda=1536) @ Wot^T  (fp32 out)
    gemm_bt_bf16<0><<<dim3(H_ / 128, M / 128), blk, 0, stream>>>(qkv, QKVW, Wot, out, H_, H_);
}

// Round 10
// 251.160 us; speedup vs baseline: 6.6297x; 1.0045x over previous
//
#include <hip/hip_runtime.h>
#include <math.h>

#define B_   2
#define S_   2048
#define H_   1024
#define NH_  16
#define NKV_ 4
#define HD_  64
#define R_   (NH_ / NKV_)   // 4 q-heads per kv-head
#define QKVW 1536           // qkv row width (q 0..1023 | k 1024..1279 | v 1280..1535)

typedef __attribute__((ext_vector_type(8))) short bf16x8;
typedef __attribute__((ext_vector_type(4))) float f32x4;

__device__ inline short f2bf(float f) {
    unsigned u = __float_as_uint(f);
    u += 0x7FFF + ((u >> 16) & 1);     // RNE to bf16
    return (short)(u >> 16);
}
__device__ inline float bf2f(short u) {
    return __uint_as_float(((unsigned)(unsigned short)u) << 16);
}

// async global->LDS, 16 B per lane; lptr is the wave-uniform chunk base,
// HW scatters lane i's 16 B at lptr + i*16 (m97/m104 semantics).
__device__ inline void gload_lds16(const void* gptr, void* lptr) {
    __builtin_amdgcn_global_load_lds(
        (const __attribute__((address_space(1))) unsigned int*)gptr,
        (__attribute__((address_space(3))) unsigned int*)lptr,
        16, 0, 0);
}

// ---------------------------------------------------------------------------
// x (fp32, row-major) -> bf16, elementwise. 8 elems/thread.
// ---------------------------------------------------------------------------
__global__ __launch_bounds__(256) void convert_x(const float* __restrict__ x,
                                                 short* __restrict__ xh) {
    int idx = blockIdx.x * 256 + threadIdx.x;
    const float4* xp = (const float4*)(x + (size_t)idx * 8);
    float4 a = xp[0], b = xp[1];
    bf16x8 o;
    o[0] = f2bf(a.x); o[1] = f2bf(a.y); o[2] = f2bf(a.z); o[3] = f2bf(a.w);
    o[4] = f2bf(b.x); o[5] = f2bf(b.y); o[6] = f2bf(b.z); o[7] = f2bf(b.w);
    *(bf16x8*)(xh + (size_t)idx * 8) = o;
}

// ---------------------------------------------------------------------------
// Wt[n][k] = bf16(W[k][n]); W is K x N fp32. 64x64 LDS-tiled transpose.
// ---------------------------------------------------------------------------
__global__ __launch_bounds__(256) void tconv(const float* __restrict__ W,
                                             short* __restrict__ Wt,
                                             int K, int N) {
    __shared__ short T[64][68];
    const int k0 = blockIdx.y * 64, n0 = blockIdx.x * 64;
    const int tid = threadIdx.x;
    const int r  = tid >> 4;
    const int c4 = (tid & 15) * 4;
#pragma unroll
    for (int t = 0; t < 4; t++) {
        int row = t * 16 + r;
        float4 v = *(const float4*)&W[(size_t)(k0 + row) * N + n0 + c4];
        T[c4 + 0][row] = f2bf(v.x);
        T[c4 + 1][row] = f2bf(v.y);
        T[c4 + 2][row] = f2bf(v.z);
        T[c4 + 3][row] = f2bf(v.w);
    }
    __syncthreads();
#pragma unroll
    for (int t = 0; t < 4; t++) {
        int row = t * 16 + r;          // n index
        short4 o = *(short4*)&T[row][c4];
        *(short4*)&Wt[(size_t)(n0 + row) * K + k0 + c4] = o;
    }
}

// ---------------------------------------------------------------------------
// V transpose pre-pass: Vtg[(b*NKV+g)*HD + d][s] = qkv v-slice (bf16).
// ---------------------------------------------------------------------------
__global__ __launch_bounds__(256) void vtrans(const short* __restrict__ qkv,
                                              short* __restrict__ Vtg) {
    int flat = blockIdx.x * 256 + threadIdx.x;
    int d  = flat & 63;
    int s8 = (flat >> 6) & (S_ / 8 - 1);
    int bg = flat >> 14;               // 0..7
    int b  = bg >> 2;
    int g  = bg & 3;
    const short* vp = qkv + ((size_t)(b * S_ + s8 * 8)) * QKVW + H_ + NKV_ * HD_ + g * HD_ + d;
    bf16x8 o;
#pragma unroll
    for (int j = 0; j < 8; j++) o[j] = vp[(size_t)j * QKVW];
    *(bf16x8*)&Vtg[((size_t)bg * HD_ + d) * S_ + s8 * 8] = o;
}

// ---------------------------------------------------------------------------
// bf16 MFMA GEMM, B^T form: C[M,N] = A[M,K] @ Bt[N,K]^T.
// 64x128 block tile (rows x cols), BK=32, 256 threads = 4 waves.
// Wave w: rows (w>>1)*32 + mi*16, cols (w&1)*64 + ni*16 (mi<2, ni<4).
// Smaller tile than 128x128 -> 2-3x the blocks -> 2-3 blocks/CU so the
// per-iter vmcnt(0)+barrier drain overlaps across blocks (m114).
// ---------------------------------------------------------------------------
template <int OUT_BF16>
__global__ __launch_bounds__(256) void gemm_bt_bf16(const short* __restrict__ A, int lda,
                                                    const short* __restrict__ Bt,
                                                    void* __restrict__ C, int ldc,
                                                    int K) {
    __shared__ short Ah[64 * 32];    // [row][k] 4 KB, unpadded (glds layout)
    __shared__ short Bh[128 * 32];   // [col][k] 8 KB

    const int tid  = threadIdx.x;
    const int w    = tid >> 6;
    const int lane = tid & 63;
    const int ln   = lane & 15;
    const int qd   = lane >> 4;
    const int wr   = w >> 1, wc = w & 1;
    const int row0 = blockIdx.y * 64;
    const int col0 = blockIdx.x * 128;

    const int sr = lane >> 2;        // 0..15
    const int sk = (lane & 3) * 8;   // k element offset

    f32x4 acc[2][4];
#pragma unroll
    for (int mi = 0; mi < 2; mi++)
#pragma unroll
        for (int ni = 0; ni < 4; ni++)
            acc[mi][ni] = (f32x4){0.f, 0.f, 0.f, 0.f};

    for (int k0 = 0; k0 < K; k0 += 32) {
        __syncthreads();   // previous iter's frag reads done
        // A: wave w stages rows w*16..w*16+15 (one glds)
        gload_lds16(A + (size_t)(row0 + w * 16 + sr) * lda + k0 + sk, &Ah[(w * 16) * 32]);
        // B: wave w stages cols w*32..w*32+31 (two glds)
        gload_lds16(Bt + (size_t)(col0 + w * 32 + sr) * K + k0 + sk, &Bh[(w * 32) * 32]);
        gload_lds16(Bt + (size_t)(col0 + w * 32 + 16 + sr) * K + k0 + sk, &Bh[(w * 32 + 16) * 32]);
        __syncthreads();   // vmcnt(0) drain inserted by compiler

        bf16x8 af[2], bfr[4];
#pragma unroll
        for (int mi = 0; mi < 2; mi++)
            af[mi] = *(const bf16x8*)&Ah[(wr * 32 + mi * 16 + ln) * 32 + qd * 8];
#pragma unroll
        for (int ni = 0; ni < 4; ni++)
            bfr[ni] = *(const bf16x8*)&Bh[(wc * 64 + ni * 16 + ln) * 32 + qd * 8];
#pragma unroll
        for (int mi = 0; mi < 2; mi++)
#pragma unroll
            for (int ni = 0; ni < 4; ni++)
                acc[mi][ni] = __builtin_amdgcn_mfma_f32_16x16x32_bf16(af[mi], bfr[ni], acc[mi][ni], 0, 0, 0);
    }

#pragma unroll
    for (int mi = 0; mi < 2; mi++)
#pragma unroll
        for (int i = 0; i < 4; i++) {
            const size_t row = row0 + wr * 32 + mi * 16 + qd * 4 + i;
            if (OUT_BF16) {
                short* Cp = (short*)C + row * ldc + col0 + wc * 64 + ln;
#pragma unroll
                for (int ni = 0; ni < 4; ni++) Cp[ni * 16] = f2bf(acc[mi][ni][i]);
            } else {
                float* Cp = (float*)C + row * ldc + col0 + wc * 64 + ln;
#pragma unroll
                for (int ni = 0; ni < 4; ni++) Cp[ni * 16] = acc[mi][ni][i];
            }
        }
}

// ---------------------------------------------------------------------------
// RoPE in-place on bf16 qkv (token stride QKVW). 8 dims/thread.
// ---------------------------------------------------------------------------
__global__ __launch_bounds__(256) void rope_bf16(short* __restrict__ qkv,
                                                 const float* __restrict__ cosb,
                                                 const float* __restrict__ sinb) {
    int idx   = blockIdx.x * 256 + threadIdx.x;   // B*S*20*4 total
    int oct   = idx & 3;
    int head  = (idx >> 2) % 20;
    int token = idx / 80;
    int spos  = token % S_;
    int d0    = oct * 8;
    int coff  = (head < NH_) ? head * HD_ : H_ + (head - NH_) * HD_;

    short* p = qkv + (size_t)token * QKVW + coff;
    bf16x8 lo = *(bf16x8*)&p[d0];
    bf16x8 hi = *(bf16x8*)&p[d0 + 32];
    const float* cp = cosb + (size_t)spos * HD_;
    const float* sp = sinb + (size_t)spos * HD_;
    bf16x8 nlo, nhi;
#pragma unroll
    for (int j = 0; j < 8; j++) {
        float x0 = bf2f(lo[j]), x1 = bf2f(hi[j]);
        float c0 = cp[d0 + j], c1 = cp[d0 + 32 + j];
        float s0 = sp[d0 + j], s1 = sp[d0 + 32 + j];
        nlo[j] = f2bf(x0 * c0 - x1 * s0);
        nhi[j] = f2bf(x1 * c1 + x0 * s1);
    }
    *(bf16x8*)&p[d0]      = nlo;
    *(bf16x8*)&p[d0 + 32] = nhi;
}

// ---------------------------------------------------------------------------
// bf16 MFMA flash attention v10 — swapped-operand QK + 64-row blocks for
// occupancy: grid (S/64, B*NH) = 1024 blocks, 27.9 KB LDS -> 4 blocks/CU
// = 16 waves/CU (4/SIMD). Single K/V buffer; inter-block overlap hides
// staging latency (m114) instead of an explicit dbuf.
// Wave w owns q-rows qt*64 + w*16 .. +15 (row = ln in softmax layout).
// ---------------------------------------------------------------------------
__global__ __launch_bounds__(256) void attn_kernel(short* __restrict__ qkv,
                                                   const short* __restrict__ Vtg,
                                                   const float* __restrict__ maskb) {
    const int tid  = threadIdx.x;
    const int w    = tid >> 6;
    const int lane = tid & 63;
    const int ln   = lane & 15;
    const int qd   = lane >> 4;

    const int by = blockIdx.y;
    const int b  = by / NH_;
    const int h  = by % NH_;
    const int g  = h / R_;
    const int bg = b * NKV_ + g;
    const int qt = (by & 1) ? (31 - (int)blockIdx.x) : (int)blockIdx.x;
    const int q0 = qt * 64;
    const int rowb = q0 + w * 16;          // wave's first q-row

    __shared__ short Ks[64 * 72];          // K  [key][dim], stride 72 (9 KB)
    __shared__ short Vt[64 * 72];          // V^T [dim][key]            (9 KB)
    __shared__ short Ps[4 * 16 * 72];      // per-wave P [row][key]     (9 KB)
    __shared__ float mskS[64];

    // ---- Q B-frags (B-layout == A-layout): row rowb+ln ----
    bf16x8 qf0, qf1;
    {
        const short* qp = qkv + (size_t)(b * S_ + rowb + ln) * QKVW + h * HD_;
        qf0 = *(const bf16x8*)&qp[qd * 8];
        qf1 = *(const bf16x8*)&qp[32 + qd * 8];
    }

    f32x4 O[4] = {};                       // [dt]: row=qd*4+i, dim=dt*16+ln
    float mrow = -1e30f, lrow = 0.0f;      // row = ln (replicated over qd)

    const int ktiles = qt + 1;
    for (int kt = 0; kt < ktiles; kt++) {
        const int base = kt * 64;

        // ---- stage K + V^T (coalesced b128 copies) + mask ----
#pragma unroll
        for (int t = 0; t < 2; t++) {
            int flat = tid + t * 256;
            int r8   = flat >> 3;
            int c8   = flat & 7;
            *(bf16x8*)&Ks[r8 * 72 + c8 * 8] =
                *(const bf16x8*)&qkv[(size_t)(b * S_ + base + r8) * QKVW + H_ + g * HD_ + c8 * 8];
            *(bf16x8*)&Vt[r8 * 72 + c8 * 8] =
                *(const bf16x8*)&Vtg[((size_t)bg * HD_ + r8) * S_ + base + c8 * 8];
        }
        if (tid < 64) mskS[tid] = maskb[b * S_ + base + tid];
        __syncthreads();

        // ---- QK^T swapped: St[kg] = S^T tile.
        // Lane (qd,ln) reg i holds S[row=rowb+ln][key=base+kg*16+qd*4+i].
        f32x4 St[4];
#pragma unroll
        for (int kg = 0; kg < 4; kg++) {
            bf16x8 ka0 = *(const bf16x8*)&Ks[(kg * 16 + ln) * 72 + qd * 8];
            bf16x8 ka1 = *(const bf16x8*)&Ks[(kg * 16 + ln) * 72 + 32 + qd * 8];
            f32x4 z = {0.f, 0.f, 0.f, 0.f};
            z = __builtin_amdgcn_mfma_f32_16x16x32_bf16(ka0, qf0, z, 0, 0, 0);
            St[kg] = __builtin_amdgcn_mfma_f32_16x16x32_bf16(ka1, qf1, z, 0, 0, 0);
        }

        // ---- per-lane mask bias for keys base+kg*16+qd*4+i ----
        float mt[4][4];
#pragma unroll
        for (int kg = 0; kg < 4; kg++) {
            float4 mv = *(const float4*)&mskS[kg * 16 + qd * 4];
            mt[kg][0] = (1.0f - mv.x) * -1e9f;
            mt[kg][1] = (1.0f - mv.y) * -1e9f;
            mt[kg][2] = (1.0f - mv.z) * -1e9f;
            mt[kg][3] = (1.0f - mv.w) * -1e9f;
        }

        // ---- online softmax (row = ln) + packed P write ----
        {
            const int qrow = rowb + ln;
            float sc[4][4];
#pragma unroll
            for (int kg = 0; kg < 4; kg++) {
                const int keyb = base + kg * 16 + qd * 4;
#pragma unroll
                for (int i = 0; i < 4; i++) {
                    float v = St[kg][i] * 0.125f + mt[kg][i];
                    sc[kg][i] = (keyb + i <= qrow) ? v : -1e30f;
                }
            }
            float mx = sc[0][0];
#pragma unroll
            for (int kg = 0; kg < 4; kg++)
#pragma unroll
                for (int i = 0; i < 4; i++) mx = fmaxf(mx, sc[kg][i]);
            mx = fmaxf(mx, __shfl_xor(mx, 16));
            mx = fmaxf(mx, __shfl_xor(mx, 32));

            float nm    = fmaxf(mrow, mx);
            float alpha = __expf(mrow - nm);
            mrow = nm;

            float ls = 0.0f;
            float pr[4][4];
#pragma unroll
            for (int kg = 0; kg < 4; kg++)
#pragma unroll
                for (int i = 0; i < 4; i++) {
                    float p = __expf(sc[kg][i] - nm);
                    pr[kg][i] = p;
                    ls += p;
                }
            ls += __shfl_xor(ls, 16);
            ls += __shfl_xor(ls, 32);
            lrow = lrow * alpha + ls;

            // rescale O (rows qd*4+i): broadcast alpha from lane qd*4+i
#pragma unroll
            for (int i = 0; i < 4; i++) {
                float av = __shfl(alpha, qd * 4 + i);
#pragma unroll
                for (int dt = 0; dt < 4; dt++) O[dt][i] *= av;
            }

            // packed P write: 4 consecutive keys per lane per kg -> b64
#pragma unroll
            for (int kg = 0; kg < 4; kg++) {
                short4 pk = { f2bf(pr[kg][0]), f2bf(pr[kg][1]),
                              f2bf(pr[kg][2]), f2bf(pr[kg][3]) };
                *(short4*)&Ps[w * 1152 + ln * 72 + kg * 16 + qd * 4] = pk;
            }
        }

        // ---- PV: O += P @ V (per-wave Ps; DS in-order within wave) ----
#pragma unroll
        for (int kc2 = 0; kc2 < 2; kc2++) {
            bf16x8 pa = *(const bf16x8*)&Ps[w * 1152 + ln * 72 + kc2 * 32 + qd * 8];
#pragma unroll
            for (int dt = 0; dt < 4; dt++) {
                bf16x8 vb = *(const bf16x8*)&Vt[(dt * 16 + ln) * 72 + kc2 * 32 + qd * 8];
                O[dt] = __builtin_amdgcn_mfma_f32_16x16x32_bf16(pa, vb, O[dt], 0, 0, 0);
            }
        }
        __syncthreads();   // frag reads done before next tile's staging
    }

    // ---- finalize: l replicated over qd; write bf16 q-slice ----
#pragma unroll
    for (int i = 0; i < 4; i++) {
        float li  = __shfl(lrow, qd * 4 + i);
        float inv = 1.0f / li;
        const int row = rowb + qd * 4 + i;
        short* op = qkv + (size_t)(b * S_ + row) * QKVW + h * HD_ + ln;
#pragma unroll
        for (int dt = 0; dt < 4; dt++) op[dt * 16] = f2bf(O[dt][i] * inv);
    }
}

// ---------------------------------------------------------------------------
extern "C" void kernel_launch(void* const* d_in, const int* in_sizes, int n_in,
                              void* d_out, int out_size, void* d_ws, size_t ws_size,
                              hipStream_t stream) {
    const float* x     = (const float*)d_in[0];
    const float* cosb  = (const float*)d_in[1];
    const float* sinb  = (const float*)d_in[2];
    const float* maskb = (const float*)d_in[3];
    const float* Wq    = (const float*)d_in[4];
    const float* Wk    = (const float*)d_in[5];
    const float* Wv    = (const float*)d_in[6];
    const float* Wo    = (const float*)d_in[7];

    const int M = B_ * S_;   // 4096

    // xh (bf16 x) lives in d_out[0, 8MB) — consumed by GEMM1 before GEMM2
    // rewrites d_out.  ws: qkv | Wqkvt | Wot | Vtg  (19 MB bf16).
    short* xh    = (short*)d_out;
    short* qkv   = (short*)d_ws;                     // [4096][1536]
    short* Wqkvt = qkv + (size_t)M * QKVW;           // [1536][1024]
    short* Wot   = Wqkvt + (size_t)QKVW * H_;        // [1024][1024]
    short* Vtg   = Wot + (size_t)H_ * H_;            // [8*64][2048]
    float* out   = (float*)d_out;

    dim3 blk(256);

    convert_x<<<dim3((M * H_) / (8 * 256)), blk, 0, stream>>>(x, xh);

    tconv<<<dim3(H_ / 64, H_ / 64), blk, 0, stream>>>(Wq, Wqkvt, H_, H_);
    tconv<<<dim3((NKV_ * HD_) / 64, H_ / 64), blk, 0, stream>>>(Wk, Wqkvt + (size_t)H_ * H_, H_, NKV_ * HD_);
    tconv<<<dim3((NKV_ * HD_) / 64, H_ / 64), blk, 0, stream>>>(Wv, Wqkvt + (size_t)(H_ + NKV_ * HD_) * H_, H_, NKV_ * HD_);
    tconv<<<dim3(H_ / 64, H_ / 64), blk, 0, stream>>>(Wo, Wot, H_, H_);

    // GEMM1: qkv = xh @ Wqkvt^T  (bf16 out)
    gemm_bt_bf16<1><<<dim3(QKVW / 128, M / 64), blk, 0, stream>>>(xh, H_, Wqkvt, qkv, QKVW, H_);

    rope_bf16<<<dim3((M * 20 * 4) / 256), blk, 0, stream>>>(qkv, cosb, sinb);

    vtrans<<<dim3((B_ * NKV_ * HD_ * (S_ / 8)) / 256), blk, 0, stream>>>(qkv, Vtg);

    attn_kernel<<<dim3(S_ / 64, B_ * NH_), blk, 0, stream>>>(qkv, Vtg, maskb);

    // GEMM2: out = attn_out(q-slice of qkv, lda=1536) @ Wot^T  (fp32 out)
    gemm_bt_bf16<0><<<dim3(H_ / 128, M / 64), blk, 0, stream>>>(qkv, QKVW, Wot, out, H_, H_);
}

// Round 11
// 226.184 us; speedup vs baseline: 7.3618x; 1.1104x over previous
//
#include <hip/hip_runtime.h>
#include <math.h>

#define B_   2
#define S_   2048
#define H_   1024
#define NH_  16
#define NKV_ 4
#define HD_  64
#define R_   (NH_ / NKV_)   // 4 q-heads per kv-head
#define QKVW 1536           // qkv row width (q 0..1023 | k 1024..1279 | v 1280..1535)

typedef __attribute__((ext_vector_type(8))) short bf16x8;
typedef __attribute__((ext_vector_type(4))) float f32x4;

__device__ inline short f2bf(float f) {
    unsigned u = __float_as_uint(f);
    u += 0x7FFF + ((u >> 16) & 1);     // RNE to bf16
    return (short)(u >> 16);
}

// async global->LDS, 16 B per lane; lptr is the wave-uniform chunk base,
// HW scatters lane i's 16 B at lptr + i*16 (m97/m104 semantics).
__device__ inline void gload_lds16(const void* gptr, void* lptr) {
    __builtin_amdgcn_global_load_lds(
        (const __attribute__((address_space(1))) unsigned int*)gptr,
        (__attribute__((address_space(3))) unsigned int*)lptr,
        16, 0, 0);
}

// ---------------------------------------------------------------------------
// All four weight transposes in one launch. 640 blocks of 64x64 tiles:
// [0,256) Wq -> Wqkvt rows 0..1023 ; [256,320) Wk -> rows 1024..1279 ;
// [320,384) Wv -> rows 1280..1535 ; [384,640) Wo -> Wot.
// ---------------------------------------------------------------------------
__global__ __launch_bounds__(256) void tconv_all(const float* __restrict__ Wq,
                                                 const float* __restrict__ Wk,
                                                 const float* __restrict__ Wv,
                                                 const float* __restrict__ Wo,
                                                 short* __restrict__ Wqkvt,
                                                 short* __restrict__ Wot) {
    __shared__ short T[64][68];
    const int bx = blockIdx.x;
    const float* W; short* Wt; int N, idx;
    if (bx < 256)      { W = Wq; Wt = Wqkvt;                     N = 1024; idx = bx; }
    else if (bx < 320) { W = Wk; Wt = Wqkvt + 1024 * 1024;       N = 256;  idx = bx - 256; }
    else if (bx < 384) { W = Wv; Wt = Wqkvt + 1280 * 1024;       N = 256;  idx = bx - 320; }
    else               { W = Wo; Wt = Wot;                       N = 1024; idx = bx - 384; }
    const int ntiles = N >> 6;
    const int n0 = (idx % ntiles) * 64;
    const int k0 = (idx / ntiles) * 64;

    const int tid = threadIdx.x;
    const int r  = tid >> 4;
    const int c4 = (tid & 15) * 4;
#pragma unroll
    for (int t = 0; t < 4; t++) {
        int row = t * 16 + r;
        float4 v = *(const float4*)&W[(size_t)(k0 + row) * N + n0 + c4];
        T[c4 + 0][row] = f2bf(v.x);
        T[c4 + 1][row] = f2bf(v.y);
        T[c4 + 2][row] = f2bf(v.z);
        T[c4 + 3][row] = f2bf(v.w);
    }
    __syncthreads();
#pragma unroll
    for (int t = 0; t < 4; t++) {
        int row = t * 16 + r;          // n index
        short4 o = *(short4*)&T[row][c4];
        *(short4*)&Wt[(size_t)(n0 + row) * 1024 + k0 + c4] = o;
    }
}

// ---------------------------------------------------------------------------
// Fused GEMM1: qkv = bf16(x) @ Wqkvt^T with
//   - A staged from fp32 x via registers (convert_x fused),
//   - RoPE applied in the fp32 epilogue for q/k cols (pairs d,d+32 are
//     thread-local: ni and ni+2),
//   - v cols written TRANSPOSED into Vtg (vtrans fused; i-regs = 4
//     consecutive rows = contiguous s -> short4).
// 64x128 tile, BK=32, 256 threads = 4 waves.
// ---------------------------------------------------------------------------
__global__ __launch_bounds__(256) void gemm1_fused(const float* __restrict__ x,
                                                   const short* __restrict__ Bt,
                                                   short* __restrict__ qkv,
                                                   short* __restrict__ Vtg,
                                                   const float* __restrict__ cosb,
                                                   const float* __restrict__ sinb) {
    __shared__ short Ah[64 * 32];    // [row][k] 4 KB
    __shared__ short Bh[128 * 32];   // [col][k] 8 KB

    const int tid  = threadIdx.x;
    const int w    = tid >> 6;
    const int lane = tid & 63;
    const int ln   = lane & 15;
    const int qd   = lane >> 4;
    const int wr   = w >> 1, wc = w & 1;
    const int row0 = blockIdx.y * 64;
    const int col0 = blockIdx.x * 128;

    const int sr = lane >> 2;        // 0..15
    const int sk = (lane & 3) * 8;   // k element offset
    const int ar  = tid >> 2;        // 0..63  (A convert-stage row)
    const int ac8 = (tid & 3) * 8;   // 0,8,16,24

    f32x4 acc[2][4];
#pragma unroll
    for (int mi = 0; mi < 2; mi++)
#pragma unroll
        for (int ni = 0; ni < 4; ni++)
            acc[mi][ni] = (f32x4){0.f, 0.f, 0.f, 0.f};

    for (int k0 = 0; k0 < 1024; k0 += 32) {
        __syncthreads();   // previous iter's frag reads done
        // A: fp32 -> bf16 in registers -> LDS
        {
            const float* xp = x + (size_t)(row0 + ar) * H_ + k0 + ac8;
            float4 a = *(const float4*)xp;
            float4 b2 = *(const float4*)(xp + 4);
            bf16x8 o;
            o[0] = f2bf(a.x);  o[1] = f2bf(a.y);  o[2] = f2bf(a.z);  o[3] = f2bf(a.w);
            o[4] = f2bf(b2.x); o[5] = f2bf(b2.y); o[6] = f2bf(b2.z); o[7] = f2bf(b2.w);
            *(bf16x8*)&Ah[ar * 32 + ac8] = o;
        }
        // B: bf16 glds (wave w stages cols w*32..w*32+31)
        gload_lds16(Bt + (size_t)(col0 + w * 32 + sr) * 1024 + k0 + sk, &Bh[(w * 32) * 32]);
        gload_lds16(Bt + (size_t)(col0 + w * 32 + 16 + sr) * 1024 + k0 + sk, &Bh[(w * 32 + 16) * 32]);
        __syncthreads();

        bf16x8 af[2], bfr[4];
#pragma unroll
        for (int mi = 0; mi < 2; mi++)
            af[mi] = *(const bf16x8*)&Ah[(wr * 32 + mi * 16 + ln) * 32 + qd * 8];
#pragma unroll
        for (int ni = 0; ni < 4; ni++)
            bfr[ni] = *(const bf16x8*)&Bh[(wc * 64 + ni * 16 + ln) * 32 + qd * 8];
#pragma unroll
        for (int mi = 0; mi < 2; mi++)
#pragma unroll
            for (int ni = 0; ni < 4; ni++)
                acc[mi][ni] = __builtin_amdgcn_mfma_f32_16x16x32_bf16(af[mi], bfr[ni], acc[mi][ni], 0, 0, 0);
    }

    const int colw = col0 + wc * 64;          // this wave's 64-col half
    if (colw < H_ + NKV_ * HD_) {
        // ---- q or k columns: RoPE in fp32, store bf16 to qkv ----
#pragma unroll
        for (int mi = 0; mi < 2; mi++)
#pragma unroll
            for (int i = 0; i < 4; i++) {
                const int row  = row0 + wr * 32 + mi * 16 + qd * 4 + i;
                const int spos = row & (S_ - 1);
                const float* cp = cosb + (size_t)spos * HD_;
                const float* sp = sinb + (size_t)spos * HD_;
                float o0[4];
#pragma unroll
                for (int ni = 0; ni < 2; ni++) {
                    const int d = ni * 16 + ln;
                    float x0 = acc[mi][ni][i], x1 = acc[mi][ni + 2][i];
                    o0[ni]     = x0 * cp[d]      - x1 * sp[d];
                    o0[ni + 2] = x1 * cp[d + 32] + x0 * sp[d + 32];
                }
                short* Cp = qkv + (size_t)row * QKVW + colw + ln;
#pragma unroll
                for (int ni = 0; ni < 4; ni++) Cp[ni * 16] = f2bf(o0[ni]);
            }
    } else {
        // ---- v columns: transposed scatter into Vtg[(b*NKV+g)*HD+d][s] ----
        const int g = (colw - (H_ + NKV_ * HD_)) >> 6;
#pragma unroll
        for (int mi = 0; mi < 2; mi++) {
            const int rbase = row0 + wr * 32 + mi * 16 + qd * 4;   // i = +0..3
            const int bg = ((rbase >> 11) * NKV_) + g;
            const int s0 = rbase & (S_ - 1);
#pragma unroll
            for (int ni = 0; ni < 4; ni++) {
                const int d = ni * 16 + ln;
                short4 pk = { f2bf(acc[mi][ni][0]), f2bf(acc[mi][ni][1]),
                              f2bf(acc[mi][ni][2]), f2bf(acc[mi][ni][3]) };
                *(short4*)&Vtg[((size_t)bg * HD_ + d) * S_ + s0] = pk;
            }
        }
    }
}

// ---------------------------------------------------------------------------
// bf16 MFMA GEMM, B^T form: C[M,N] = A[M,K] @ Bt[N,K]^T (fp32 out).
// 64x128 tile, BK=32, 256 threads. Used for the output projection.
// ---------------------------------------------------------------------------
__global__ __launch_bounds__(256) void gemm2_bt(const short* __restrict__ A, int lda,
                                                const short* __restrict__ Bt,
                                                float* __restrict__ C, int ldc,
                                                int K) {
    __shared__ short Ah[64 * 32];
    __shared__ short Bh[128 * 32];

    const int tid  = threadIdx.x;
    const int w    = tid >> 6;
    const int lane = tid & 63;
    const int ln   = lane & 15;
    const int qd   = lane >> 4;
    const int wr   = w >> 1, wc = w & 1;
    const int row0 = blockIdx.y * 64;
    const int col0 = blockIdx.x * 128;

    const int sr = lane >> 2;
    const int sk = (lane & 3) * 8;

    f32x4 acc[2][4];
#pragma unroll
    for (int mi = 0; mi < 2; mi++)
#pragma unroll
        for (int ni = 0; ni < 4; ni++)
            acc[mi][ni] = (f32x4){0.f, 0.f, 0.f, 0.f};

    for (int k0 = 0; k0 < K; k0 += 32) {
        __syncthreads();
        gload_lds16(A + (size_t)(row0 + w * 16 + sr) * lda + k0 + sk, &Ah[(w * 16) * 32]);
        gload_lds16(Bt + (size_t)(col0 + w * 32 + sr) * K + k0 + sk, &Bh[(w * 32) * 32]);
        gload_lds16(Bt + (size_t)(col0 + w * 32 + 16 + sr) * K + k0 + sk, &Bh[(w * 32 + 16) * 32]);
        __syncthreads();

        bf16x8 af[2], bfr[4];
#pragma unroll
        for (int mi = 0; mi < 2; mi++)
            af[mi] = *(const bf16x8*)&Ah[(wr * 32 + mi * 16 + ln) * 32 + qd * 8];
#pragma unroll
        for (int ni = 0; ni < 4; ni++)
            bfr[ni] = *(const bf16x8*)&Bh[(wc * 64 + ni * 16 + ln) * 32 + qd * 8];
#pragma unroll
        for (int mi = 0; mi < 2; mi++)
#pragma unroll
            for (int ni = 0; ni < 4; ni++)
                acc[mi][ni] = __builtin_amdgcn_mfma_f32_16x16x32_bf16(af[mi], bfr[ni], acc[mi][ni], 0, 0, 0);
    }

#pragma unroll
    for (int mi = 0; mi < 2; mi++)
#pragma unroll
        for (int i = 0; i < 4; i++) {
            const size_t row = row0 + wr * 32 + mi * 16 + qd * 4 + i;
            float* Cp = C + row * ldc + col0 + wc * 64 + ln;
#pragma unroll
            for (int ni = 0; ni < 4; ni++) Cp[ni * 16] = acc[mi][ni][i];
        }
}

// ---------------------------------------------------------------------------
// bf16 MFMA flash attention v11 = v9 (swapped-operand QK, reg-dbuf K/V,
// one barrier/tile; measured best 101 us) + two wave-uniform skips:
//  (a) ballot-guarded rescale: when no row's running max moved, skip the
//      4-shfl alpha broadcast + O/l rescale entirely;
//  (b) skip QK/softmax/PV for tiles fully causal-masked for this wave
//      (base > rowb+31) — waves 0/1 of each block on the last tile.
// grid = (S/128, B*NH) = 512 blocks; block = 256 (4 waves x 32 q-rows).
// ---------------------------------------------------------------------------
__global__ __launch_bounds__(256) void attn_kernel(short* __restrict__ qkv,
                                                   const short* __restrict__ Vtg,
                                                   const float* __restrict__ maskb) {
    const int tid  = threadIdx.x;
    const int w    = tid >> 6;
    const int lane = tid & 63;
    const int ln   = lane & 15;
    const int qd   = lane >> 4;

    const int by = blockIdx.y;
    const int b  = by / NH_;
    const int h  = by % NH_;
    const int g  = h / R_;
    const int bg = b * NKV_ + g;
    const int qt = (by & 1) ? (15 - (int)blockIdx.x) : (int)blockIdx.x;
    const int q0 = qt * 128;
    const int rowb = q0 + w * 32;          // wave's first q-row

    __shared__ short Ks[2][64 * 72];       // K  [key][dim], stride 72
    __shared__ short Vt[2][64 * 72];       // V^T [dim][key]
    __shared__ short Ps[4 * 32 * 72];      // per-wave P [row 0..31][key]
    __shared__ float mskS[2][64];

    const int f0r = tid >> 3,         f0c = (tid & 7) * 8;
    const int f1r = (tid + 256) >> 3, f1c = ((tid + 256) & 7) * 8;

    // ---- Q B-frags (B-layout == A-layout): rows rowb+rg*16+ln ----
    bf16x8 qf[2][2];
#pragma unroll
    for (int rg = 0; rg < 2; rg++) {
        const short* qp = qkv + (size_t)(b * S_ + rowb + rg * 16 + ln) * QKVW + h * HD_;
        qf[rg][0] = *(const bf16x8*)&qp[qd * 8];
        qf[rg][1] = *(const bf16x8*)&qp[32 + qd * 8];
    }

    f32x4 O[2][4] = {};
    float mrow[2] = {-1e30f, -1e30f};      // per-rg, row = ln (replicated over qd)
    float lrow[2] = {0.0f, 0.0f};

    const int ktiles = 2 * qt + 2;

    // ---- stage tile 0 into buffer 0 ----
    {
        *(bf16x8*)&Ks[0][f0r * 72 + f0c] =
            *(const bf16x8*)&qkv[(size_t)(b * S_ + f0r) * QKVW + H_ + g * HD_ + f0c];
        *(bf16x8*)&Ks[0][f1r * 72 + f1c] =
            *(const bf16x8*)&qkv[(size_t)(b * S_ + f1r) * QKVW + H_ + g * HD_ + f1c];
        *(bf16x8*)&Vt[0][f0r * 72 + f0c] =
            *(const bf16x8*)&Vtg[((size_t)bg * HD_ + f0r) * S_ + f0c];
        *(bf16x8*)&Vt[0][f1r * 72 + f1c] =
            *(const bf16x8*)&Vtg[((size_t)bg * HD_ + f1r) * S_ + f1c];
        if (tid < 64) mskS[0][tid] = maskb[b * S_ + tid];
    }
    __syncthreads();

    int cur = 0;
    for (int kt = 0; kt < ktiles; kt++) {
        const int base = kt * 64;
        const bool pf = (kt + 1 < ktiles);

        // ---- prefetch tile kt+1 into registers (no wait) ----
        bf16x8 pk0, pk1, pv0, pv1;
        float pm = 0.0f;
        if (pf) {
            const int nb = base + 64;
            pk0 = *(const bf16x8*)&qkv[(size_t)(b * S_ + nb + f0r) * QKVW + H_ + g * HD_ + f0c];
            pk1 = *(const bf16x8*)&qkv[(size_t)(b * S_ + nb + f1r) * QKVW + H_ + g * HD_ + f1c];
            pv0 = *(const bf16x8*)&Vtg[((size_t)bg * HD_ + f0r) * S_ + nb + f0c];
            pv1 = *(const bf16x8*)&Vtg[((size_t)bg * HD_ + f1r) * S_ + nb + f1c];
            if (tid < 64) pm = maskb[b * S_ + nb + tid];
        }

        if (base <= rowb + 31) {   // wave-uniform: tile has unmasked keys
            // ---- QK^T swapped: St[rg][kg] = S^T tile ----
            f32x4 St[2][4];
#pragma unroll
            for (int kg = 0; kg < 4; kg++) {
                bf16x8 ka0 = *(const bf16x8*)&Ks[cur][(kg * 16 + ln) * 72 + qd * 8];
                bf16x8 ka1 = *(const bf16x8*)&Ks[cur][(kg * 16 + ln) * 72 + 32 + qd * 8];
#pragma unroll
                for (int rg = 0; rg < 2; rg++) {
                    f32x4 z = {0.f, 0.f, 0.f, 0.f};
                    z = __builtin_amdgcn_mfma_f32_16x16x32_bf16(ka0, qf[rg][0], z, 0, 0, 0);
                    St[rg][kg] = __builtin_amdgcn_mfma_f32_16x16x32_bf16(ka1, qf[rg][1], z, 0, 0, 0);
                }
            }

            // ---- per-lane mask bias for keys base+kg*16+qd*4+i ----
            float mt[4][4];
#pragma unroll
            for (int kg = 0; kg < 4; kg++) {
                float4 mv = *(const float4*)&mskS[cur][kg * 16 + qd * 4];
                mt[kg][0] = (1.0f - mv.x) * -1e9f;
                mt[kg][1] = (1.0f - mv.y) * -1e9f;
                mt[kg][2] = (1.0f - mv.z) * -1e9f;
                mt[kg][3] = (1.0f - mv.w) * -1e9f;
            }

            // ---- online softmax per rg (row = ln) + packed P write ----
#pragma unroll
            for (int rg = 0; rg < 2; rg++) {
                const int qrow = rowb + rg * 16 + ln;
                float sc[4][4];
#pragma unroll
                for (int kg = 0; kg < 4; kg++) {
                    const int keyb = base + kg * 16 + qd * 4;
#pragma unroll
                    for (int i = 0; i < 4; i++) {
                        float v = St[rg][kg][i] * 0.125f + mt[kg][i];
                        sc[kg][i] = (keyb + i <= qrow) ? v : -1e30f;
                    }
                }
                float mx = sc[0][0];
#pragma unroll
                for (int kg = 0; kg < 4; kg++)
#pragma unroll
                    for (int i = 0; i < 4; i++) mx = fmaxf(mx, sc[kg][i]);
                mx = fmaxf(mx, __shfl_xor(mx, 16));
                mx = fmaxf(mx, __shfl_xor(mx, 32));

                float nm = fmaxf(mrow[rg], mx);
                // ballot-guard: only rescale when some row's max moved
                if (__ballot(nm > mrow[rg])) {
                    float alpha = __expf(mrow[rg] - nm);
                    lrow[rg] *= alpha;
#pragma unroll
                    for (int i = 0; i < 4; i++) {
                        float av = __shfl(alpha, qd * 4 + i);
#pragma unroll
                        for (int dt = 0; dt < 4; dt++) O[rg][dt][i] *= av;
                    }
                }
                mrow[rg] = nm;

                float ls = 0.0f;
                float pr[4][4];
#pragma unroll
                for (int kg = 0; kg < 4; kg++)
#pragma unroll
                    for (int i = 0; i < 4; i++) {
                        float p = __expf(sc[kg][i] - nm);
                        pr[kg][i] = p;
                        ls += p;
                    }
                ls += __shfl_xor(ls, 16);
                ls += __shfl_xor(ls, 32);
                lrow[rg] += ls;

#pragma unroll
                for (int kg = 0; kg < 4; kg++) {
                    short4 pk = { f2bf(pr[kg][0]), f2bf(pr[kg][1]),
                                  f2bf(pr[kg][2]), f2bf(pr[kg][3]) };
                    *(short4*)&Ps[w * 2304 + (rg * 16 + ln) * 72 + kg * 16 + qd * 4] = pk;
                }
            }

            // ---- PV: O[rg] += P[rg] @ V ; V B-frags shared across rgs ----
#pragma unroll
            for (int kc2 = 0; kc2 < 2; kc2++) {
                bf16x8 pa0 = *(const bf16x8*)&Ps[w * 2304 + (ln)      * 72 + kc2 * 32 + qd * 8];
                bf16x8 pa1 = *(const bf16x8*)&Ps[w * 2304 + (16 + ln) * 72 + kc2 * 32 + qd * 8];
#pragma unroll
                for (int dt = 0; dt < 4; dt++) {
                    bf16x8 vb = *(const bf16x8*)&Vt[cur][(dt * 16 + ln) * 72 + kc2 * 32 + qd * 8];
                    O[0][dt] = __builtin_amdgcn_mfma_f32_16x16x32_bf16(pa0, vb, O[0][dt], 0, 0, 0);
                    O[1][dt] = __builtin_amdgcn_mfma_f32_16x16x32_bf16(pa1, vb, O[1][dt], 0, 0, 0);
                }
            }
        }

        // ---- write prefetched tile into the other buffer ----
        if (pf) {
            const int nxt = cur ^ 1;
            *(bf16x8*)&Ks[nxt][f0r * 72 + f0c] = pk0;
            *(bf16x8*)&Ks[nxt][f1r * 72 + f1c] = pk1;
            *(bf16x8*)&Vt[nxt][f0r * 72 + f0c] = pv0;
            *(bf16x8*)&Vt[nxt][f1r * 72 + f1c] = pv1;
            if (tid < 64) mskS[nxt][tid] = pm;
        }
        __syncthreads();
        cur ^= 1;
    }

    // ---- finalize: l replicated over qd; write bf16 into q-slice ----
#pragma unroll
    for (int rg = 0; rg < 2; rg++)
#pragma unroll
        for (int i = 0; i < 4; i++) {
            float li  = __shfl(lrow[rg], qd * 4 + i);
            float inv = 1.0f / li;
            const int row = rowb + rg * 16 + qd * 4 + i;
            short* op = qkv + (size_t)(b * S_ + row) * QKVW + h * HD_ + ln;
#pragma unroll
            for (int dt = 0; dt < 4; dt++) op[dt * 16] = f2bf(O[rg][dt][i] * inv);
        }
}

// ---------------------------------------------------------------------------
extern "C" void kernel_launch(void* const* d_in, const int* in_sizes, int n_in,
                              void* d_out, int out_size, void* d_ws, size_t ws_size,
                              hipStream_t stream) {
    const float* x     = (const float*)d_in[0];
    const float* cosb  = (const float*)d_in[1];
    const float* sinb  = (const float*)d_in[2];
    const float* maskb = (const float*)d_in[3];
    const float* Wq    = (const float*)d_in[4];
    const float* Wk    = (const float*)d_in[5];
    const float* Wv    = (const float*)d_in[6];
    const float* Wo    = (const float*)d_in[7];

    const int M = B_ * S_;   // 4096

    // ws: qkv | Wqkvt | Wot | Vtg  (19.9 MB bf16). d_out used only for out.
    short* qkv   = (short*)d_ws;                     // [4096][1536]
    short* Wqkvt = qkv + (size_t)M * QKVW;           // [1536][1024]
    short* Wot   = Wqkvt + (size_t)QKVW * H_;        // [1024][1024]
    short* Vtg   = Wot + (size_t)H_ * H_;            // [8*64][2048]
    float* out   = (float*)d_out;

    dim3 blk(256);

    tconv_all<<<dim3(640), blk, 0, stream>>>(Wq, Wk, Wv, Wo, Wqkvt, Wot);

    // GEMM1 fused: qkv(q,k roped) + Vtg, straight from fp32 x
    gemm1_fused<<<dim3(QKVW / 128, M / 64), blk, 0, stream>>>(x, Wqkvt, qkv, Vtg, cosb, sinb);

    attn_kernel<<<dim3(S_ / 128, B_ * NH_), blk, 0, stream>>>(qkv, Vtg, maskb);

    // GEMM2: out = attn_out(q-slice of qkv, lda=1536) @ Wot^T  (fp32 out)
    gemm2_bt<<<dim3(H_ / 128, M / 64), blk, 0, stream>>>(qkv, QKVW, Wot, out, H_, H_);
}